// Round 7
// baseline (1020.732 us; speedup 1.0000x reference)
//
#include <hip/hip_runtime.h>

#define Bn 4
#define Nn 40
#define NCUBE 64000   // 40^3
#define ROWS 128      // rows per out/full tile
#define BPB  500      // out/full blocks per batch
#define SROWS 64      // rows per embed/sums tile
#define SBPB 1000     // embed/sums blocks per batch

typedef _Float16 f16;
typedef __attribute__((ext_vector_type(8)))  _Float16 f16x8;
typedef __attribute__((ext_vector_type(4)))  _Float16 f16x4;
typedef __attribute__((ext_vector_type(16))) float    f32x16;

// ---------------- workspace layout (bytes) ----------------
// tier BIG : 0 sums | 2048 xf[Bn*NCUBE*128] f16 | WBOFF_BIG weights
// tier SMALL: 0 sums | 2560 weights
#define OFF_WI1 0
#define OFF_WI2 16384
#define OFF_WE  32768
#define OFF_WO1 49152
#define WB_HALFS 114688
#define WB_BYTES (WB_HALFS*2)
#define XF_BYTES (Bn*NCUBE*128*2)          // 65,536,000
#define WBOFF_BIG (2048 + XF_BYTES)
#define WS_BIG    (WBOFF_BIG + WB_BYTES)
#define WBOFF_SMALL 2560

// 16B-granule XOR swizzle for [rows][256]-f16 LDS tiles (f16 units).
__device__ __forceinline__ int swz8(int row, int colg) {
    return row*256 + (((colg & ~7) | ((colg ^ row) & 7)) << 3);
}
__device__ __forceinline__ int swzofs(int row, int col) {
    return swz8(row, col >> 3) + (col & 7);
}

// Weight A-fragment for mfma_f32_32x32x16_f16 with SWAPPED operands
// (arg0 = W-frag): lane l, j holds W[kt*16 + 8*(l>>5) + j][nt*32 + (l&31)].
// D maps: chan = nt*32 + (reg&3)+8*(reg>>2)+4*(l>>5), act_row = base + (l&31).
template<bool PRE>
__device__ __forceinline__ f16x8 load_wfrag(const f16* __restrict__ WF,
                                            const float* __restrict__ W,
                                            int N, int NT, int kt, int nt, int l) {
    if constexpr (PRE) {
        return *(const f16x8*)(WF + ((kt*NT + nt)*64 + l)*8);
    } else {
        const int col = nt*32 + (l & 31);
        const int k0  = kt*16 + 8*(l >> 5);
        f16x8 r;
        #pragma unroll
        for (int j = 0; j < 8; ++j) r[j] = (f16)W[(k0 + j)*N + col];
        return r;
    }
}

// Activation B-fragment via swizzled ds_read_b128.
__device__ __forceinline__ f16x8 lds_af(const f16* hb, int rowbase, int areag, int kt, int l) {
    return *(const f16x8*)&hb[swz8(rowbase + (l & 31), areag + 2*kt + (l >> 5))];
}

__device__ __forceinline__ bool row_valid(int e, const unsigned char* mlds) {
    int k = e % Nn, ij = e / Nn, j = ij % Nn, i = ij / Nn;
    return (i < j) && (j < k) && mlds[i] && mlds[j] && mlds[k];
}

// ---------------------------------------------------------------------------
// One-time weight conversion into A-fragment layout (f16).
// ---------------------------------------------------------------------------
__global__ __launch_bounds__(256)
void prep_kernel(const float* __restrict__ Wi1, const float* __restrict__ Wi2,
                 const float* __restrict__ We,  const float* __restrict__ Wo1,
                 f16* __restrict__ WB) {
    int id = blockIdx.x*256 + threadIdx.x;   // 0..14335
    const float* W; int NT, N; f16* WF; int fid;
    if (id < 2048)      { W = Wi1; NT = 4; N = 128; WF = WB+OFF_WI1; fid = id; }
    else if (id < 4096) { W = Wi2; NT = 4; N = 128; WF = WB+OFF_WI2; fid = id-2048; }
    else if (id < 6144) { W = We;  NT = 4; N = 128; WF = WB+OFF_WE;  fid = id-4096; }
    else                { W = Wo1; NT = 8; N = 256; WF = WB+OFF_WO1; fid = id-6144; }
    int frag = fid >> 6, l = fid & 63;
    int nt = frag % NT, kt = frag / NT;
    int col = nt*32 + (l & 31), k0 = kt*16 + 8*(l >> 5);
    #pragma unroll
    for (int j = 0; j < 8; ++j) WF[frag*512 + l*8 + j] = (f16)W[(k0 + j)*N + col];
}

// ---------------------------------------------------------------------------
// K1 "embed": stages 1-2 for ALL rows; writes xf (f16) + fused masked exp-sums.
// 64-row tiles, 8 waves = 2 row-groups (wr) x 4 col-slices (wc). 32x32x16 MFMA.
// Small reg set -> high occupancy; s1/s2 computed exactly once per row.
// ---------------------------------------------------------------------------
template<bool PRE>
__global__ __launch_bounds__(512, 4)
void embed_kernel(const float* __restrict__ x, const unsigned char* __restrict__ mask,
                  const float* __restrict__ Wi1, const float* __restrict__ bi1,
                  const float* __restrict__ Wi2, const float* __restrict__ bi2,
                  float* __restrict__ sums, f16* __restrict__ xfg,
                  const f16* __restrict__ WB)
{
    const int tid = threadIdx.x;
    const int l = tid & 63, w = tid >> 6, lr = l & 31, lh = l >> 5;
    const int wr = w >> 2, wc = w & 3;
    const int b = blockIdx.x / SBPB;
    const int e0 = (blockIdx.x % SBPB) * SROWS;

    __shared__ __align__(16) f16 hb[SROWS*256];   // 32 KB
    __shared__ unsigned char mlds[Nn];

    if (tid < Nn) mlds[tid] = mask[b*Nn + tid];

    // phA: x tile -> f16 LDS cols [128,256)
    #pragma unroll
    for (int p = 0; p < 2; ++p) {
        const int row = p*32 + (tid >> 4);
        const int c0  = (tid & 15)*8;
        const long base = ((long)(b*NCUBE + e0 + row))*128 + c0;
        const float4 x0 = *(const float4*)&x[base];
        const float4 x1 = *(const float4*)&x[base + 4];
        f16x8 v; v[0]=(f16)x0.x; v[1]=(f16)x0.y; v[2]=(f16)x0.z; v[3]=(f16)x0.w;
                 v[4]=(f16)x1.x; v[5]=(f16)x1.y; v[6]=(f16)x1.z; v[7]=(f16)x1.w;
        *(f16x8*)&hb[swzofs(row, 128 + c0)] = v;
    }
    __syncthreads();

    const bool rv = row_valid(e0 + 32*wr + lr, mlds);

    // stage 1: h1 = relu(x @ Wi1 + bi1) -> cols [0,128)
    f32x16 acc;
    #pragma unroll
    for (int rg = 0; rg < 4; ++rg) {
        const float4 bv = *(const float4*)(bi1 + 32*wc + 8*rg + 4*lh);
        acc[rg*4+0]=bv.x; acc[rg*4+1]=bv.y; acc[rg*4+2]=bv.z; acc[rg*4+3]=bv.w;
    }
    #pragma unroll
    for (int kt = 0; kt < 8; ++kt) {
        const f16x8 wf = load_wfrag<PRE>(WB+OFF_WI1, Wi1, 128, 4, kt, wc, l);
        const f16x8 af = lds_af(hb, 32*wr, 16, kt, l);
        acc = __builtin_amdgcn_mfma_f32_32x32x16_f16(wf, af, acc, 0, 0, 0);
    }
    #pragma unroll
    for (int rg = 0; rg < 4; ++rg) {
        f16x4 v;
        #pragma unroll
        for (int q = 0; q < 4; ++q) v[q] = (f16)fmaxf(acc[rg*4+q], 0.f);
        *(f16x4*)&hb[swzofs(32*wr + lr, 32*wc + 8*rg + 4*lh)] = v;
    }
    __syncthreads();

    // stage 2: xf = h1 @ Wi2 + bi2
    #pragma unroll
    for (int rg = 0; rg < 4; ++rg) {
        const float4 bv = *(const float4*)(bi2 + 32*wc + 8*rg + 4*lh);
        acc[rg*4+0]=bv.x; acc[rg*4+1]=bv.y; acc[rg*4+2]=bv.z; acc[rg*4+3]=bv.w;
    }
    #pragma unroll
    for (int kt = 0; kt < 8; ++kt) {
        const f16x8 wf = load_wfrag<PRE>(WB+OFF_WI2, Wi2, 128, 4, kt, wc, l);
        const f16x8 af = lds_af(hb, 32*wr, 0, kt, l);
        acc = __builtin_amdgcn_mfma_f32_32x32x16_f16(wf, af, acc, 0, 0, 0);
    }

    // round xf to f16, stash into [128,256) (x dead after s1 barrier),
    // and accumulate masked exp of the SAME f16 values (consistent with K2).
    float s[16];
    #pragma unroll
    for (int rg = 0; rg < 4; ++rg) {
        f16x4 v;
        #pragma unroll
        for (int q = 0; q < 4; ++q) {
            v[q] = (f16)acc[rg*4+q];
            s[rg*4+q] = rv ? __expf((float)v[q]) : 0.0f;
        }
        *(f16x4*)&hb[swzofs(32*wr + lr, 128 + 32*wc + 8*rg + 4*lh)] = v;
    }
    #pragma unroll
    for (int r = 0; r < 16; ++r) {
        float v = s[r];
        v += __shfl_xor(v, 1); v += __shfl_xor(v, 2);
        v += __shfl_xor(v, 4); v += __shfl_xor(v, 8); v += __shfl_xor(v, 16);
        if (lr == 0) atomicAdd(&sums[b*128 + 32*wc + 8*(r>>2) + 4*lh + (r&3)], v);
    }
    __syncthreads();

    // copy xf tile -> global (coalesced 16B/lane)
    #pragma unroll
    for (int p = 0; p < 2; ++p) {
        const int row = p*32 + (tid >> 4);
        const int c0  = (tid & 15)*8;
        const f16x8 v = *(const f16x8*)&hb[swzofs(row, 128 + c0)];
        *(f16x8*)&xfg[((long)(b*NCUBE + e0 + row))*128 + c0] = v;
    }
}

// ---------------------------------------------------------------------------
// K2 "out": loads xf, computes s3 (xi), a = valid?exp(xf)/sum:0, s4, s5.
// 128-row tiles, 8 waves = 2 row-groups (wr: 64 rows, mt-pair of 32) x 4 wc.
// ---------------------------------------------------------------------------
template<bool PRE>
__global__ __launch_bounds__(512, 4)
void out_kernel(const f16* __restrict__ xfg, const unsigned char* __restrict__ mask,
                const float* __restrict__ We,
                const float* __restrict__ Wo1, const float* __restrict__ bo1,
                const float* __restrict__ Wo2, const float* __restrict__ bo2,
                const float* __restrict__ sums, const f16* __restrict__ WB,
                float* __restrict__ out)
{
    const int tid = threadIdx.x;
    const int l = tid & 63, w = tid >> 6, lr = l & 31, lh = l >> 5;
    const int wr = w >> 2, wc = w & 3;
    const int b = blockIdx.x / BPB;
    const int e0 = (blockIdx.x % BPB) * ROWS;

    __shared__ __align__(16) f16 hb[ROWS*256];   // 64 KB
    __shared__ float red[8][64];
    __shared__ unsigned char mlds[Nn];

    if (tid < Nn) mlds[tid] = mask[b*Nn + tid];

    // phA: xf tile -> LDS cols [128,256)
    #pragma unroll
    for (int p = 0; p < 4; ++p) {
        const int row = p*32 + (tid >> 4);
        const int c0  = (tid & 15)*8;
        const f16x8 v = *(const f16x8*)&xfg[((long)(b*NCUBE + e0 + row))*128 + c0];
        *(f16x8*)&hb[swzofs(row, 128 + c0)] = v;
    }
    __syncthreads();

    bool valid[2];
    #pragma unroll
    for (int mt = 0; mt < 2; ++mt)
        valid[mt] = row_valid(e0 + 64*wr + 32*mt + lr, mlds);

    // ---- stage 3: xi = relu(xf @ We); a*xi -> cols [0,128) ----
    {
        f32x16 acc3[2];
        #pragma unroll
        for (int mt = 0; mt < 2; ++mt)
            #pragma unroll
            for (int r = 0; r < 16; ++r) acc3[mt][r] = 0.f;
        #pragma unroll
        for (int kt = 0; kt < 8; ++kt) {
            const f16x8 wf = load_wfrag<PRE>(WB+OFF_WE, We, 128, 4, kt, wc, l);
            #pragma unroll
            for (int mt = 0; mt < 2; ++mt) {
                const f16x8 af = lds_af(hb, 64*wr + 32*mt, 16, kt, l);
                acc3[mt] = __builtin_amdgcn_mfma_f32_32x32x16_f16(wf, af, acc3[mt], 0, 0, 0);
            }
        }
        #pragma unroll
        for (int rg = 0; rg < 4; ++rg) {
            const float4 sv = *(const float4*)(sums + b*128 + 32*wc + 8*rg + 4*lh);
            const float rinv[4] = {1.f/sv.x, 1.f/sv.y, 1.f/sv.z, 1.f/sv.w};
            #pragma unroll
            for (int mt = 0; mt < 2; ++mt) {
                const f16x4 xq = *(const f16x4*)&hb[swzofs(64*wr + 32*mt + lr,
                                                           128 + 32*wc + 8*rg + 4*lh)];
                f16x4 v;
                #pragma unroll
                for (int q = 0; q < 4; ++q) {
                    const float aa = valid[mt] ? __expf((float)xq[q]) * rinv[q] : 0.0f;
                    v[q] = (f16)(aa * fmaxf(acc3[mt][rg*4+q], 0.f));
                }
                *(f16x4*)&hb[swzofs(64*wr + 32*mt + lr, 32*wc + 8*rg + 4*lh)] = v;
            }
        }
    }
    __syncthreads();

    // ---- stage 4: g = relu(h @ Wo1 + bo1), K=256 over h=[a*xi | xf] ----
    f32x16 acc4[2][2];
    #pragma unroll
    for (int ntl = 0; ntl < 2; ++ntl)
        #pragma unroll
        for (int rg = 0; rg < 4; ++rg) {
            const float4 bv = *(const float4*)(bo1 + 64*wc + 32*ntl + 8*rg + 4*lh);
            #pragma unroll
            for (int mt = 0; mt < 2; ++mt) {
                acc4[mt][ntl][rg*4+0]=bv.x; acc4[mt][ntl][rg*4+1]=bv.y;
                acc4[mt][ntl][rg*4+2]=bv.z; acc4[mt][ntl][rg*4+3]=bv.w;
            }
        }
    #pragma unroll
    for (int kt = 0; kt < 16; ++kt) {
        f16x8 of0 = load_wfrag<PRE>(WB+OFF_WO1, Wo1, 256, 8, kt, 2*wc+0, l);
        f16x8 of1 = load_wfrag<PRE>(WB+OFF_WO1, Wo1, 256, 8, kt, 2*wc+1, l);
        #pragma unroll
        for (int mt = 0; mt < 2; ++mt) {
            const f16x8 af = lds_af(hb, 64*wr + 32*mt, 0, kt, l);
            acc4[mt][0] = __builtin_amdgcn_mfma_f32_32x32x16_f16(of0, af, acc4[mt][0], 0, 0, 0);
            acc4[mt][1] = __builtin_amdgcn_mfma_f32_32x32x16_f16(of1, af, acc4[mt][1], 0, 0, 0);
        }
    }

    // ---- stage 5: out = relu(g) @ Wo2 + bo2, reduce 256 -> 1 per row ----
    {
        float outp[2] = {0.f, 0.f};
        #pragma unroll
        for (int ntl = 0; ntl < 2; ++ntl)
            #pragma unroll
            for (int rg = 0; rg < 4; ++rg) {
                const float4 wv = *(const float4*)(Wo2 + 64*wc + 32*ntl + 8*rg + 4*lh);
                #pragma unroll
                for (int mt = 0; mt < 2; ++mt) {
                    outp[mt] += fmaxf(acc4[mt][ntl][rg*4+0], 0.f)*wv.x
                              + fmaxf(acc4[mt][ntl][rg*4+1], 0.f)*wv.y
                              + fmaxf(acc4[mt][ntl][rg*4+2], 0.f)*wv.z
                              + fmaxf(acc4[mt][ntl][rg*4+3], 0.f)*wv.w;
                }
            }
        #pragma unroll
        for (int mt = 0; mt < 2; ++mt) outp[mt] += __shfl_xor(outp[mt], 32);
        if (l < 32) {
            red[w][lr]      = outp[0];
            red[w][32 + lr] = outp[1];
        }
        __syncthreads();
        if (tid < ROWS) {
            const int wr2 = tid >> 6, idx = tid & 63;
            out[(long)b*NCUBE + e0 + tid] =
                red[wr2*4+0][idx] + red[wr2*4+1][idx] +
                red[wr2*4+2][idx] + red[wr2*4+3][idx] + bo2[0];
        }
    }
}

// ---------------------------------------------------------------------------
// Fallback tier (ws too small for xf): R6 structure — dense sums + full.
// ---------------------------------------------------------------------------
template<bool PRE>
__global__ __launch_bounds__(512, 4)
void sums_kernel(const float* __restrict__ x, const unsigned char* __restrict__ mask,
                 const float* __restrict__ Wi1, const float* __restrict__ bi1,
                 const float* __restrict__ Wi2, const float* __restrict__ bi2,
                 float* __restrict__ sums, const f16* __restrict__ WB)
{
    const int tid = threadIdx.x;
    const int l = tid & 63, w = tid >> 6, lr = l & 31, lh = l >> 5;
    const int wr = w >> 2, wc = w & 3;
    const int b = blockIdx.x / SBPB;
    const int e0 = (blockIdx.x % SBPB) * SROWS;

    __shared__ __align__(16) f16 hb[SROWS*256];
    __shared__ unsigned char mlds[Nn];
    __shared__ int anyv;

    if (tid < Nn) mlds[tid] = mask[b*Nn + tid];
    if (tid == 0) anyv = 0;
    __syncthreads();

    const bool rv = row_valid(e0 + 32*wr + lr, mlds);
    if (__any(rv)) anyv = 1;
    __syncthreads();
    if (!anyv) return;

    #pragma unroll
    for (int p = 0; p < 2; ++p) {
        const int row = p*32 + (tid >> 4);
        const int c0  = (tid & 15)*8;
        const long base = ((long)(b*NCUBE + e0 + row))*128 + c0;
        const float4 x0 = *(const float4*)&x[base];
        const float4 x1 = *(const float4*)&x[base + 4];
        f16x8 v; v[0]=(f16)x0.x; v[1]=(f16)x0.y; v[2]=(f16)x0.z; v[3]=(f16)x0.w;
                 v[4]=(f16)x1.x; v[5]=(f16)x1.y; v[6]=(f16)x1.z; v[7]=(f16)x1.w;
        *(f16x8*)&hb[swzofs(row, 128 + c0)] = v;
    }
    __syncthreads();

    f32x16 acc;
    #pragma unroll
    for (int rg = 0; rg < 4; ++rg) {
        const float4 bv = *(const float4*)(bi1 + 32*wc + 8*rg + 4*lh);
        acc[rg*4+0]=bv.x; acc[rg*4+1]=bv.y; acc[rg*4+2]=bv.z; acc[rg*4+3]=bv.w;
    }
    #pragma unroll
    for (int kt = 0; kt < 8; ++kt) {
        const f16x8 wf = load_wfrag<PRE>(WB+OFF_WI1, Wi1, 128, 4, kt, wc, l);
        const f16x8 af = lds_af(hb, 32*wr, 16, kt, l);
        acc = __builtin_amdgcn_mfma_f32_32x32x16_f16(wf, af, acc, 0, 0, 0);
    }
    #pragma unroll
    for (int rg = 0; rg < 4; ++rg) {
        f16x4 v;
        #pragma unroll
        for (int q = 0; q < 4; ++q) v[q] = (f16)fmaxf(acc[rg*4+q], 0.f);
        *(f16x4*)&hb[swzofs(32*wr + lr, 32*wc + 8*rg + 4*lh)] = v;
    }
    __syncthreads();

    #pragma unroll
    for (int rg = 0; rg < 4; ++rg) {
        const float4 bv = *(const float4*)(bi2 + 32*wc + 8*rg + 4*lh);
        acc[rg*4+0]=bv.x; acc[rg*4+1]=bv.y; acc[rg*4+2]=bv.z; acc[rg*4+3]=bv.w;
    }
    #pragma unroll
    for (int kt = 0; kt < 8; ++kt) {
        const f16x8 wf = load_wfrag<PRE>(WB+OFF_WI2, Wi2, 128, 4, kt, wc, l);
        const f16x8 af = lds_af(hb, 32*wr, 0, kt, l);
        acc = __builtin_amdgcn_mfma_f32_32x32x16_f16(wf, af, acc, 0, 0, 0);
    }

    float s[16];
    #pragma unroll
    for (int r = 0; r < 16; ++r) s[r] = rv ? __expf(acc[r]) : 0.0f;
    #pragma unroll
    for (int r = 0; r < 16; ++r) {
        float v = s[r];
        v += __shfl_xor(v, 1); v += __shfl_xor(v, 2);
        v += __shfl_xor(v, 4); v += __shfl_xor(v, 8); v += __shfl_xor(v, 16);
        if (lr == 0) atomicAdd(&sums[b*128 + 32*wc + 8*(r>>2) + 4*lh + (r&3)], v);
    }
}

template<bool PRE>
__global__ __launch_bounds__(512, 4)
void full_kernel(const float* __restrict__ x, const unsigned char* __restrict__ mask,
                 const float* __restrict__ Wi1, const float* __restrict__ bi1,
                 const float* __restrict__ Wi2, const float* __restrict__ bi2,
                 const float* __restrict__ We,
                 const float* __restrict__ Wo1, const float* __restrict__ bo1,
                 const float* __restrict__ Wo2, const float* __restrict__ bo2,
                 const float* __restrict__ sums, const f16* __restrict__ WB,
                 float* __restrict__ out)
{
    const int tid = threadIdx.x;
    const int l = tid & 63, w = tid >> 6, lr = l & 31, lh = l >> 5;
    const int wr = w >> 2, wc = w & 3;
    const int b = blockIdx.x / BPB;
    const int e0 = (blockIdx.x % BPB) * ROWS;

    __shared__ __align__(16) f16 hb[ROWS*256];
    __shared__ float red[8][64];
    __shared__ unsigned char mlds[Nn];

    if (tid < Nn) mlds[tid] = mask[b*Nn + tid];

    #pragma unroll
    for (int p = 0; p < 4; ++p) {
        const int row = p*32 + (tid >> 4);
        const int c0  = (tid & 15)*8;
        const long base = ((long)(b*NCUBE + e0 + row))*128 + c0;
        const float4 x0 = *(const float4*)&x[base];
        const float4 x1 = *(const float4*)&x[base + 4];
        f16x8 v; v[0]=(f16)x0.x; v[1]=(f16)x0.y; v[2]=(f16)x0.z; v[3]=(f16)x0.w;
                 v[4]=(f16)x1.x; v[5]=(f16)x1.y; v[6]=(f16)x1.z; v[7]=(f16)x1.w;
        *(f16x8*)&hb[swzofs(row, 128 + c0)] = v;
    }
    __syncthreads();

    bool valid[2];
    #pragma unroll
    for (int mt = 0; mt < 2; ++mt)
        valid[mt] = row_valid(e0 + 64*wr + 32*mt + lr, mlds);

    {
        f32x16 acc1[2];
        #pragma unroll
        for (int rg = 0; rg < 4; ++rg) {
            const float4 bv = *(const float4*)(bi1 + 32*wc + 8*rg + 4*lh);
            #pragma unroll
            for (int mt = 0; mt < 2; ++mt) {
                acc1[mt][rg*4+0]=bv.x; acc1[mt][rg*4+1]=bv.y;
                acc1[mt][rg*4+2]=bv.z; acc1[mt][rg*4+3]=bv.w;
            }
        }
        #pragma unroll
        for (int kt = 0; kt < 8; ++kt) {
            const f16x8 wf = load_wfrag<PRE>(WB+OFF_WI1, Wi1, 128, 4, kt, wc, l);
            #pragma unroll
            for (int mt = 0; mt < 2; ++mt) {
                const f16x8 af = lds_af(hb, 64*wr + 32*mt, 16, kt, l);
                acc1[mt] = __builtin_amdgcn_mfma_f32_32x32x16_f16(wf, af, acc1[mt], 0, 0, 0);
            }
        }
        #pragma unroll
        for (int mt = 0; mt < 2; ++mt)
            #pragma unroll
            for (int rg = 0; rg < 4; ++rg) {
                f16x4 v;
                #pragma unroll
                for (int q = 0; q < 4; ++q) v[q] = (f16)fmaxf(acc1[mt][rg*4+q], 0.f);
                *(f16x4*)&hb[swzofs(64*wr + 32*mt + lr, 32*wc + 8*rg + 4*lh)] = v;
            }
    }
    __syncthreads();

    f32x16 acc2[2];
    {
        #pragma unroll
        for (int rg = 0; rg < 4; ++rg) {
            const float4 bv = *(const float4*)(bi2 + 32*wc + 8*rg + 4*lh);
            #pragma unroll
            for (int mt = 0; mt < 2; ++mt) {
                acc2[mt][rg*4+0]=bv.x; acc2[mt][rg*4+1]=bv.y;
                acc2[mt][rg*4+2]=bv.z; acc2[mt][rg*4+3]=bv.w;
            }
        }
        #pragma unroll
        for (int kt = 0; kt < 8; ++kt) {
            const f16x8 wf = load_wfrag<PRE>(WB+OFF_WI2, Wi2, 128, 4, kt, wc, l);
            #pragma unroll
            for (int mt = 0; mt < 2; ++mt) {
                const f16x8 af = lds_af(hb, 64*wr + 32*mt, 0, kt, l);
                acc2[mt] = __builtin_amdgcn_mfma_f32_32x32x16_f16(wf, af, acc2[mt], 0, 0, 0);
            }
        }
        #pragma unroll
        for (int mt = 0; mt < 2; ++mt)
            #pragma unroll
            for (int rg = 0; rg < 4; ++rg) {
                f16x4 v;
                #pragma unroll
                for (int q = 0; q < 4; ++q) v[q] = (f16)acc2[mt][rg*4+q];
                *(f16x4*)&hb[swzofs(64*wr + 32*mt + lr, 128 + 32*wc + 8*rg + 4*lh)] = v;
            }
        #pragma unroll
        for (int rg = 0; rg < 4; ++rg) {
            const float4 sv = *(const float4*)(sums + b*128 + 32*wc + 8*rg + 4*lh);
            const float rinv[4] = {1.f/sv.x, 1.f/sv.y, 1.f/sv.z, 1.f/sv.w};
            #pragma unroll
            for (int mt = 0; mt < 2; ++mt)
                #pragma unroll
                for (int q = 0; q < 4; ++q)
                    acc2[mt][rg*4+q] = valid[mt] ? __expf(acc2[mt][rg*4+q]) * rinv[q] : 0.0f;
        }
    }
    __syncthreads();

    {
        f32x16 acc3[2];
        #pragma unroll
        for (int mt = 0; mt < 2; ++mt)
            #pragma unroll
            for (int r = 0; r < 16; ++r) acc3[mt][r] = 0.f;
        #pragma unroll
        for (int kt = 0; kt < 8; ++kt) {
            const f16x8 wf = load_wfrag<PRE>(WB+OFF_WE, We, 128, 4, kt, wc, l);
            #pragma unroll
            for (int mt = 0; mt < 2; ++mt) {
                const f16x8 af = lds_af(hb, 64*wr + 32*mt, 16, kt, l);
                acc3[mt] = __builtin_amdgcn_mfma_f32_32x32x16_f16(wf, af, acc3[mt], 0, 0, 0);
            }
        }
        #pragma unroll
        for (int mt = 0; mt < 2; ++mt)
            #pragma unroll
            for (int rg = 0; rg < 4; ++rg) {
                f16x4 v;
                #pragma unroll
                for (int q = 0; q < 4; ++q)
                    v[q] = (f16)(acc2[mt][rg*4+q] * fmaxf(acc3[mt][rg*4+q], 0.f));
                *(f16x4*)&hb[swzofs(64*wr + 32*mt + lr, 32*wc + 8*rg + 4*lh)] = v;
            }
    }
    __syncthreads();

    f32x16 acc4[2][2];
    #pragma unroll
    for (int ntl = 0; ntl < 2; ++ntl)
        #pragma unroll
        for (int rg = 0; rg < 4; ++rg) {
            const float4 bv = *(const float4*)(bo1 + 64*wc + 32*ntl + 8*rg + 4*lh);
            #pragma unroll
            for (int mt = 0; mt < 2; ++mt) {
                acc4[mt][ntl][rg*4+0]=bv.x; acc4[mt][ntl][rg*4+1]=bv.y;
                acc4[mt][ntl][rg*4+2]=bv.z; acc4[mt][ntl][rg*4+3]=bv.w;
            }
        }
    #pragma unroll
    for (int kt = 0; kt < 16; ++kt) {
        f16x8 of0 = load_wfrag<PRE>(WB+OFF_WO1, Wo1, 256, 8, kt, 2*wc+0, l);
        f16x8 of1 = load_wfrag<PRE>(WB+OFF_WO1, Wo1, 256, 8, kt, 2*wc+1, l);
        #pragma unroll
        for (int mt = 0; mt < 2; ++mt) {
            const f16x8 af = lds_af(hb, 64*wr + 32*mt, 0, kt, l);
            acc4[mt][0] = __builtin_amdgcn_mfma_f32_32x32x16_f16(of0, af, acc4[mt][0], 0, 0, 0);
            acc4[mt][1] = __builtin_amdgcn_mfma_f32_32x32x16_f16(of1, af, acc4[mt][1], 0, 0, 0);
        }
    }

    {
        float outp[2] = {0.f, 0.f};
        #pragma unroll
        for (int ntl = 0; ntl < 2; ++ntl)
            #pragma unroll
            for (int rg = 0; rg < 4; ++rg) {
                const float4 wv = *(const float4*)(Wo2 + 64*wc + 32*ntl + 8*rg + 4*lh);
                #pragma unroll
                for (int mt = 0; mt < 2; ++mt) {
                    outp[mt] += fmaxf(acc4[mt][ntl][rg*4+0], 0.f)*wv.x
                              + fmaxf(acc4[mt][ntl][rg*4+1], 0.f)*wv.y
                              + fmaxf(acc4[mt][ntl][rg*4+2], 0.f)*wv.z
                              + fmaxf(acc4[mt][ntl][rg*4+3], 0.f)*wv.w;
                }
            }
        #pragma unroll
        for (int mt = 0; mt < 2; ++mt) outp[mt] += __shfl_xor(outp[mt], 32);
        if (l < 32) {
            red[w][lr]      = outp[0];
            red[w][32 + lr] = outp[1];
        }
        __syncthreads();
        if (tid < ROWS) {
            const int wr2 = tid >> 6, idx = tid & 63;
            out[(long)b*NCUBE + e0 + tid] =
                red[wr2*4+0][idx] + red[wr2*4+1][idx] +
                red[wr2*4+2][idx] + red[wr2*4+3][idx] + bo2[0];
        }
    }
}

extern "C" void kernel_launch(void* const* d_in, const int* in_sizes, int n_in,
                              void* d_out, int out_size, void* d_ws, size_t ws_size,
                              hipStream_t stream) {
    const float*         x    = (const float*)d_in[0];
    const unsigned char* mask = (const unsigned char*)d_in[1];
    const float* Wi1 = (const float*)d_in[2];
    const float* bi1 = (const float*)d_in[3];
    const float* Wi2 = (const float*)d_in[4];
    const float* bi2 = (const float*)d_in[5];
    const float* We  = (const float*)d_in[6];
    const float* Wo1 = (const float*)d_in[7];
    const float* bo1 = (const float*)d_in[8];
    const float* Wo2 = (const float*)d_in[9];
    const float* bo2 = (const float*)d_in[10];
    float* out  = (float*)d_out;
    float* sums = (float*)d_ws;

    hipMemsetAsync(d_ws, 0, 2048, stream);

    if (ws_size >= (size_t)WS_BIG) {
        f16* xfg = (f16*)((char*)d_ws + 2048);
        f16* WB  = (f16*)((char*)d_ws + WBOFF_BIG);
        prep_kernel<<<56, 256, 0, stream>>>(Wi1, Wi2, We, Wo1, WB);
        embed_kernel<true><<<Bn*SBPB, 512, 0, stream>>>(x, mask, Wi1, bi1, Wi2, bi2,
                                                        sums, xfg, WB);
        out_kernel<true><<<Bn*BPB, 512, 0, stream>>>(xfg, mask, We, Wo1, bo1, Wo2, bo2,
                                                     sums, WB, out);
    } else if (ws_size >= (size_t)(WBOFF_SMALL + WB_BYTES)) {
        f16* WB = (f16*)((char*)d_ws + WBOFF_SMALL);
        prep_kernel<<<56, 256, 0, stream>>>(Wi1, Wi2, We, Wo1, WB);
        sums_kernel<true><<<Bn*SBPB, 512, 0, stream>>>(x, mask, Wi1, bi1, Wi2, bi2, sums, WB);
        full_kernel<true><<<Bn*BPB, 512, 0, stream>>>(x, mask, Wi1, bi1, Wi2, bi2, We,
                                                      Wo1, bo1, Wo2, bo2, sums, WB, out);
    } else {
        sums_kernel<false><<<Bn*SBPB, 512, 0, stream>>>(x, mask, Wi1, bi1, Wi2, bi2,
                                                        sums, nullptr);
        full_kernel<false><<<Bn*BPB, 512, 0, stream>>>(x, mask, Wi1, bi1, Wi2, bi2, We,
                                                       Wo1, bo1, Wo2, bo2, sums, nullptr, out);
    }
}

// Round 8
// 338.884 us; speedup vs baseline: 3.0120x; 3.0120x over previous
//
#include <hip/hip_runtime.h>

#define Bn 4
#define Nn 40
#define NCUBE 64000   // 40^3
#define ROWS 128      // rows per out/full tile
#define BPB  500      // out/full blocks per batch
#define SROWS 64      // rows per embed/sums tile
#define SBPB 1000     // embed/sums blocks per batch

typedef _Float16 f16;
typedef __attribute__((ext_vector_type(8)))  _Float16 f16x8;
typedef __attribute__((ext_vector_type(4)))  _Float16 f16x4;
typedef __attribute__((ext_vector_type(16))) float    f32x16;

// ---------------- workspace layout (bytes) ----------------
// BIG : 0 sums[Bn*128] | 2048 psums[Bn*SBPB*128] | xf[Bn*NCUBE*128 f16] | WB
// SMALL: 0 sums | 2560 WB
#define OFF_WI1 0
#define OFF_WI2 16384
#define OFF_WE  32768
#define OFF_WO1 49152
#define WB_HALFS 114688
#define WB_BYTES (WB_HALFS*2)
#define PS_BYTES (Bn*SBPB*128*4)           // 2,048,000
#define XF_BYTES (Bn*NCUBE*128*2)          // 65,536,000
#define XFOFF_BIG (2048 + PS_BYTES)
#define WBOFF_BIG (XFOFF_BIG + XF_BYTES)
#define WS_BIG    (WBOFF_BIG + WB_BYTES)
#define WBOFF_SMALL 2560

// 16B-granule XOR swizzle for [rows][256]-f16 LDS tiles (f16 units).
__device__ __forceinline__ int swz8(int row, int colg) {
    return row*256 + (((colg & ~7) | ((colg ^ row) & 7)) << 3);
}
__device__ __forceinline__ int swzofs(int row, int col) {
    return swz8(row, col >> 3) + (col & 7);
}

// Weight A-fragment for mfma_f32_32x32x16_f16 with SWAPPED operands
// (arg0 = W-frag): lane l, j holds W[kt*16 + 8*(l>>5) + j][nt*32 + (l&31)].
// D maps: chan = nt*32 + (reg&3)+8*(reg>>2)+4*(l>>5), act_row = base + (l&31).
template<bool PRE>
__device__ __forceinline__ f16x8 load_wfrag(const f16* __restrict__ WF,
                                            const float* __restrict__ W,
                                            int N, int NT, int kt, int nt, int l) {
    if constexpr (PRE) {
        return *(const f16x8*)(WF + ((kt*NT + nt)*64 + l)*8);
    } else {
        const int col = nt*32 + (l & 31);
        const int k0  = kt*16 + 8*(l >> 5);
        f16x8 r;
        #pragma unroll
        for (int j = 0; j < 8; ++j) r[j] = (f16)W[(k0 + j)*N + col];
        return r;
    }
}

// Activation B-fragment via swizzled ds_read_b128.
__device__ __forceinline__ f16x8 lds_af(const f16* hb, int rowbase, int areag, int kt, int l) {
    return *(const f16x8*)&hb[swz8(rowbase + (l & 31), areag + 2*kt + (l >> 5))];
}

__device__ __forceinline__ bool row_valid(int e, const unsigned char* mlds) {
    int k = e % Nn, ij = e / Nn, j = ij % Nn, i = ij / Nn;
    return (i < j) && (j < k) && mlds[i] && mlds[j] && mlds[k];
}

// ---------------------------------------------------------------------------
// One-time weight conversion into A-fragment layout (f16).
// ---------------------------------------------------------------------------
__global__ __launch_bounds__(256)
void prep_kernel(const float* __restrict__ Wi1, const float* __restrict__ Wi2,
                 const float* __restrict__ We,  const float* __restrict__ Wo1,
                 f16* __restrict__ WB) {
    int id = blockIdx.x*256 + threadIdx.x;   // 0..14335
    const float* W; int NT, N; f16* WF; int fid;
    if (id < 2048)      { W = Wi1; NT = 4; N = 128; WF = WB+OFF_WI1; fid = id; }
    else if (id < 4096) { W = Wi2; NT = 4; N = 128; WF = WB+OFF_WI2; fid = id-2048; }
    else if (id < 6144) { W = We;  NT = 4; N = 128; WF = WB+OFF_WE;  fid = id-4096; }
    else                { W = Wo1; NT = 8; N = 256; WF = WB+OFF_WO1; fid = id-6144; }
    int frag = fid >> 6, l = fid & 63;
    int nt = frag % NT, kt = frag / NT;
    int col = nt*32 + (l & 31), k0 = kt*16 + 8*(l >> 5);
    #pragma unroll
    for (int j = 0; j < 8; ++j) WF[frag*512 + l*8 + j] = (f16)W[(k0 + j)*N + col];
}

// ---------------------------------------------------------------------------
// K1 "embed": stages 1-2 for ALL rows; writes xf (f16) + per-block partial
// exp-sums (NO global atomics — R7's 823us was a contended-atomic storm:
// 4000 blocks x 256 device-atomics into 512B. G12: block-reduce first).
// ---------------------------------------------------------------------------
template<bool PRE>
__global__ __launch_bounds__(512, 4)
void embed_kernel(const float* __restrict__ x, const unsigned char* __restrict__ mask,
                  const float* __restrict__ Wi1, const float* __restrict__ bi1,
                  const float* __restrict__ Wi2, const float* __restrict__ bi2,
                  float* __restrict__ psums, f16* __restrict__ xfg,
                  const f16* __restrict__ WB)
{
    const int tid = threadIdx.x;
    const int l = tid & 63, w = tid >> 6, lr = l & 31, lh = l >> 5;
    const int wr = w >> 2, wc = w & 3;
    const int b   = blockIdx.x / SBPB;
    const int blk = blockIdx.x % SBPB;
    const int e0  = blk * SROWS;

    __shared__ __align__(16) f16 hb[SROWS*256];   // 32 KB
    __shared__ float sred[128];
    __shared__ unsigned char mlds[Nn];

    if (tid < Nn) mlds[tid] = mask[b*Nn + tid];

    // phA: x tile -> f16 LDS cols [128,256)
    #pragma unroll
    for (int p = 0; p < 2; ++p) {
        const int row = p*32 + (tid >> 4);
        const int c0  = (tid & 15)*8;
        const long base = ((long)(b*NCUBE + e0 + row))*128 + c0;
        const float4 x0 = *(const float4*)&x[base];
        const float4 x1 = *(const float4*)&x[base + 4];
        f16x8 v; v[0]=(f16)x0.x; v[1]=(f16)x0.y; v[2]=(f16)x0.z; v[3]=(f16)x0.w;
                 v[4]=(f16)x1.x; v[5]=(f16)x1.y; v[6]=(f16)x1.z; v[7]=(f16)x1.w;
        *(f16x8*)&hb[swzofs(row, 128 + c0)] = v;
    }
    __syncthreads();

    const bool rv = row_valid(e0 + 32*wr + lr, mlds);

    // stage 1: h1 = relu(x @ Wi1 + bi1) -> cols [0,128). W-frags hoisted.
    f32x16 acc;
    {
        f16x8 wfr[8];
        #pragma unroll
        for (int kt = 0; kt < 8; ++kt)
            wfr[kt] = load_wfrag<PRE>(WB+OFF_WI1, Wi1, 128, 4, kt, wc, l);
        #pragma unroll
        for (int rg = 0; rg < 4; ++rg) {
            const float4 bv = *(const float4*)(bi1 + 32*wc + 8*rg + 4*lh);
            acc[rg*4+0]=bv.x; acc[rg*4+1]=bv.y; acc[rg*4+2]=bv.z; acc[rg*4+3]=bv.w;
        }
        #pragma unroll
        for (int kt = 0; kt < 8; ++kt) {
            const f16x8 af = lds_af(hb, 32*wr, 16, kt, l);
            acc = __builtin_amdgcn_mfma_f32_32x32x16_f16(wfr[kt], af, acc, 0, 0, 0);
        }
        #pragma unroll
        for (int rg = 0; rg < 4; ++rg) {
            f16x4 v;
            #pragma unroll
            for (int q = 0; q < 4; ++q) v[q] = (f16)fmaxf(acc[rg*4+q], 0.f);
            *(f16x4*)&hb[swzofs(32*wr + lr, 32*wc + 8*rg + 4*lh)] = v;
        }
    }
    __syncthreads();

    // stage 2: xf = h1 @ Wi2 + bi2. W-frags hoisted.
    {
        f16x8 wfr[8];
        #pragma unroll
        for (int kt = 0; kt < 8; ++kt)
            wfr[kt] = load_wfrag<PRE>(WB+OFF_WI2, Wi2, 128, 4, kt, wc, l);
        #pragma unroll
        for (int rg = 0; rg < 4; ++rg) {
            const float4 bv = *(const float4*)(bi2 + 32*wc + 8*rg + 4*lh);
            acc[rg*4+0]=bv.x; acc[rg*4+1]=bv.y; acc[rg*4+2]=bv.z; acc[rg*4+3]=bv.w;
        }
        #pragma unroll
        for (int kt = 0; kt < 8; ++kt) {
            const f16x8 af = lds_af(hb, 32*wr, 0, kt, l);
            acc = __builtin_amdgcn_mfma_f32_32x32x16_f16(wfr[kt], af, acc, 0, 0, 0);
        }
    }

    // round xf to f16, stash into [128,256), masked exp of SAME f16 values
    float red16[16];
    #pragma unroll
    for (int rg = 0; rg < 4; ++rg) {
        f16x4 v;
        #pragma unroll
        for (int q = 0; q < 4; ++q) {
            v[q] = (f16)acc[rg*4+q];
            red16[rg*4+q] = rv ? __expf((float)v[q]) : 0.0f;
        }
        *(f16x4*)&hb[swzofs(32*wr + lr, 128 + 32*wc + 8*rg + 4*lh)] = v;
    }
    // butterfly over the 32 rows of this wave-half: all lanes hold the half-sum
    #pragma unroll
    for (int r = 0; r < 16; ++r) {
        float v = red16[r];
        v += __shfl_xor(v, 1); v += __shfl_xor(v, 2);
        v += __shfl_xor(v, 4); v += __shfl_xor(v, 8); v += __shfl_xor(v, 16);
        red16[r] = v;
    }
    // cross-wave combine in LDS: wr=0 waves write, wr=1 waves add (no atomics)
    __syncthreads();
    if (wr == 0 && lr == 0) {
        #pragma unroll
        for (int r = 0; r < 16; ++r)
            sred[32*wc + 8*(r>>2) + 4*lh + (r&3)] = red16[r];
    }
    __syncthreads();
    if (wr == 1 && lr == 0) {
        #pragma unroll
        for (int r = 0; r < 16; ++r)
            sred[32*wc + 8*(r>>2) + 4*lh + (r&3)] += red16[r];
    }
    __syncthreads();
    if (tid < 128)
        psums[((long)(b*SBPB + blk))*128 + tid] = sred[tid];

    // copy xf tile -> global (coalesced 16B/lane)
    #pragma unroll
    for (int p = 0; p < 2; ++p) {
        const int row = p*32 + (tid >> 4);
        const int c0  = (tid & 15)*8;
        const f16x8 v = *(const f16x8*)&hb[swzofs(row, 128 + c0)];
        *(f16x8*)&xfg[((long)(b*NCUBE + e0 + row))*128 + c0] = v;
    }
}

// ---------------------------------------------------------------------------
// Reduce psums (Bn x SBPB x 128) -> sums (Bn x 128). One block per batch.
// ---------------------------------------------------------------------------
__global__ __launch_bounds__(512)
void sumreduce_kernel(const float* __restrict__ psums, float* __restrict__ sums) {
    const int b = blockIdx.x;
    const int c = threadIdx.x & 127, q = threadIdx.x >> 7;   // 4 chunks of groups
    float s = 0.f;
    for (int g = q; g < SBPB; g += 4)
        s += psums[((long)(b*SBPB + g))*128 + c];
    __shared__ float tmp[4][128];
    tmp[q][c] = s;
    __syncthreads();
    if (q == 0) sums[b*128 + c] = tmp[0][c] + tmp[1][c] + tmp[2][c] + tmp[3][c];
}

// ---------------------------------------------------------------------------
// K2 "out": loads xf, computes s3 (xi), a = valid?exp(xf)/sum:0, s4, s5.
// 128-row tiles, 8 waves = 2 row-groups x 4 col-slices. W hoist + s4 prefetch.
// ---------------------------------------------------------------------------
template<bool PRE>
__global__ __launch_bounds__(512, 4)
void out_kernel(const f16* __restrict__ xfg, const unsigned char* __restrict__ mask,
                const float* __restrict__ We,
                const float* __restrict__ Wo1, const float* __restrict__ bo1,
                const float* __restrict__ Wo2, const float* __restrict__ bo2,
                const float* __restrict__ sums, const f16* __restrict__ WB,
                float* __restrict__ out)
{
    const int tid = threadIdx.x;
    const int l = tid & 63, w = tid >> 6, lr = l & 31, lh = l >> 5;
    const int wr = w >> 2, wc = w & 3;
    const int b = blockIdx.x / BPB;
    const int e0 = (blockIdx.x % BPB) * ROWS;

    __shared__ __align__(16) f16 hb[ROWS*256];   // 64 KB
    __shared__ float red[8][64];
    __shared__ unsigned char mlds[Nn];

    if (tid < Nn) mlds[tid] = mask[b*Nn + tid];

    // phA: xf tile -> LDS cols [128,256)
    #pragma unroll
    for (int p = 0; p < 4; ++p) {
        const int row = p*32 + (tid >> 4);
        const int c0  = (tid & 15)*8;
        const f16x8 v = *(const f16x8*)&xfg[((long)(b*NCUBE + e0 + row))*128 + c0];
        *(f16x8*)&hb[swzofs(row, 128 + c0)] = v;
    }
    __syncthreads();

    bool valid[2];
    #pragma unroll
    for (int mt = 0; mt < 2; ++mt)
        valid[mt] = row_valid(e0 + 64*wr + 32*mt + lr, mlds);

    // ---- stage 3: xi = relu(xf @ We); a*xi -> cols [0,128). W hoisted. ----
    {
        f16x8 wfr[8];
        #pragma unroll
        for (int kt = 0; kt < 8; ++kt)
            wfr[kt] = load_wfrag<PRE>(WB+OFF_WE, We, 128, 4, kt, wc, l);
        f32x16 acc3[2];
        #pragma unroll
        for (int mt = 0; mt < 2; ++mt)
            #pragma unroll
            for (int r = 0; r < 16; ++r) acc3[mt][r] = 0.f;
        #pragma unroll
        for (int kt = 0; kt < 8; ++kt) {
            #pragma unroll
            for (int mt = 0; mt < 2; ++mt) {
                const f16x8 af = lds_af(hb, 64*wr + 32*mt, 16, kt, l);
                acc3[mt] = __builtin_amdgcn_mfma_f32_32x32x16_f16(wfr[kt], af, acc3[mt], 0, 0, 0);
            }
        }
        #pragma unroll
        for (int rg = 0; rg < 4; ++rg) {
            const float4 sv = *(const float4*)(sums + b*128 + 32*wc + 8*rg + 4*lh);
            const float rinv[4] = {1.f/sv.x, 1.f/sv.y, 1.f/sv.z, 1.f/sv.w};
            #pragma unroll
            for (int mt = 0; mt < 2; ++mt) {
                const f16x4 xq = *(const f16x4*)&hb[swzofs(64*wr + 32*mt + lr,
                                                           128 + 32*wc + 8*rg + 4*lh)];
                f16x4 v;
                #pragma unroll
                for (int q = 0; q < 4; ++q) {
                    const float aa = valid[mt] ? __expf((float)xq[q]) * rinv[q] : 0.0f;
                    v[q] = (f16)(aa * fmaxf(acc3[mt][rg*4+q], 0.f));
                }
                *(f16x4*)&hb[swzofs(64*wr + 32*mt + lr, 32*wc + 8*rg + 4*lh)] = v;
            }
        }
    }
    __syncthreads();

    // ---- stage 4: g = relu(h @ Wo1 + bo1), K=256, 2-deep W prefetch ----
    f32x16 acc4[2][2];
    #pragma unroll
    for (int ntl = 0; ntl < 2; ++ntl)
        #pragma unroll
        for (int rg = 0; rg < 4; ++rg) {
            const float4 bv = *(const float4*)(bo1 + 64*wc + 32*ntl + 8*rg + 4*lh);
            #pragma unroll
            for (int mt = 0; mt < 2; ++mt) {
                acc4[mt][ntl][rg*4+0]=bv.x; acc4[mt][ntl][rg*4+1]=bv.y;
                acc4[mt][ntl][rg*4+2]=bv.z; acc4[mt][ntl][rg*4+3]=bv.w;
            }
        }
    {
        f16x8 of0 = load_wfrag<PRE>(WB+OFF_WO1, Wo1, 256, 8, 0, 2*wc+0, l);
        f16x8 of1 = load_wfrag<PRE>(WB+OFF_WO1, Wo1, 256, 8, 0, 2*wc+1, l);
        #pragma unroll
        for (int kt = 0; kt < 16; ++kt) {
            f16x8 nf0, nf1;
            if (kt < 15) {
                nf0 = load_wfrag<PRE>(WB+OFF_WO1, Wo1, 256, 8, kt+1, 2*wc+0, l);
                nf1 = load_wfrag<PRE>(WB+OFF_WO1, Wo1, 256, 8, kt+1, 2*wc+1, l);
            }
            #pragma unroll
            for (int mt = 0; mt < 2; ++mt) {
                const f16x8 af = lds_af(hb, 64*wr + 32*mt, 0, kt, l);
                acc4[mt][0] = __builtin_amdgcn_mfma_f32_32x32x16_f16(of0, af, acc4[mt][0], 0, 0, 0);
                acc4[mt][1] = __builtin_amdgcn_mfma_f32_32x32x16_f16(of1, af, acc4[mt][1], 0, 0, 0);
            }
            of0 = nf0; of1 = nf1;
        }
    }

    // ---- stage 5: out = relu(g) @ Wo2 + bo2, reduce 256 -> 1 per row ----
    {
        float outp[2] = {0.f, 0.f};
        #pragma unroll
        for (int ntl = 0; ntl < 2; ++ntl)
            #pragma unroll
            for (int rg = 0; rg < 4; ++rg) {
                const float4 wv = *(const float4*)(Wo2 + 64*wc + 32*ntl + 8*rg + 4*lh);
                #pragma unroll
                for (int mt = 0; mt < 2; ++mt) {
                    outp[mt] += fmaxf(acc4[mt][ntl][rg*4+0], 0.f)*wv.x
                              + fmaxf(acc4[mt][ntl][rg*4+1], 0.f)*wv.y
                              + fmaxf(acc4[mt][ntl][rg*4+2], 0.f)*wv.z
                              + fmaxf(acc4[mt][ntl][rg*4+3], 0.f)*wv.w;
                }
            }
        #pragma unroll
        for (int mt = 0; mt < 2; ++mt) outp[mt] += __shfl_xor(outp[mt], 32);
        if (l < 32) {
            red[w][lr]      = outp[0];
            red[w][32 + lr] = outp[1];
        }
        __syncthreads();
        if (tid < ROWS) {
            const int wr2 = tid >> 6, idx = tid & 63;
            out[(long)b*NCUBE + e0 + tid] =
                red[wr2*4+0][idx] + red[wr2*4+1][idx] +
                red[wr2*4+2][idx] + red[wr2*4+3][idx] + bo2[0];
        }
    }
}

// ---------------------------------------------------------------------------
// Fallback tier (ws too small for xf+psums): R6-style dense sums + full.
// (Never runs on this harness — BIG tier proven granted in R7.)
// ---------------------------------------------------------------------------
template<bool PRE>
__global__ __launch_bounds__(512, 4)
void sums_kernel(const float* __restrict__ x, const unsigned char* __restrict__ mask,
                 const float* __restrict__ Wi1, const float* __restrict__ bi1,
                 const float* __restrict__ Wi2, const float* __restrict__ bi2,
                 float* __restrict__ sums, const f16* __restrict__ WB)
{
    const int tid = threadIdx.x;
    const int l = tid & 63, w = tid >> 6, lr = l & 31, lh = l >> 5;
    const int wr = w >> 2, wc = w & 3;
    const int b = blockIdx.x / SBPB;
    const int e0 = (blockIdx.x % SBPB) * SROWS;

    __shared__ __align__(16) f16 hb[SROWS*256];
    __shared__ unsigned char mlds[Nn];
    __shared__ int anyv;

    if (tid < Nn) mlds[tid] = mask[b*Nn + tid];
    if (tid == 0) anyv = 0;
    __syncthreads();

    const bool rv = row_valid(e0 + 32*wr + lr, mlds);
    if (__any(rv)) anyv = 1;
    __syncthreads();
    if (!anyv) return;

    #pragma unroll
    for (int p = 0; p < 2; ++p) {
        const int row = p*32 + (tid >> 4);
        const int c0  = (tid & 15)*8;
        const long base = ((long)(b*NCUBE + e0 + row))*128 + c0;
        const float4 x0 = *(const float4*)&x[base];
        const float4 x1 = *(const float4*)&x[base + 4];
        f16x8 v; v[0]=(f16)x0.x; v[1]=(f16)x0.y; v[2]=(f16)x0.z; v[3]=(f16)x0.w;
                 v[4]=(f16)x1.x; v[5]=(f16)x1.y; v[6]=(f16)x1.z; v[7]=(f16)x1.w;
        *(f16x8*)&hb[swzofs(row, 128 + c0)] = v;
    }
    __syncthreads();

    f32x16 acc;
    #pragma unroll
    for (int rg = 0; rg < 4; ++rg) {
        const float4 bv = *(const float4*)(bi1 + 32*wc + 8*rg + 4*lh);
        acc[rg*4+0]=bv.x; acc[rg*4+1]=bv.y; acc[rg*4+2]=bv.z; acc[rg*4+3]=bv.w;
    }
    #pragma unroll
    for (int kt = 0; kt < 8; ++kt) {
        const f16x8 wf = load_wfrag<PRE>(WB+OFF_WI1, Wi1, 128, 4, kt, wc, l);
        const f16x8 af = lds_af(hb, 32*wr, 16, kt, l);
        acc = __builtin_amdgcn_mfma_f32_32x32x16_f16(wf, af, acc, 0, 0, 0);
    }
    #pragma unroll
    for (int rg = 0; rg < 4; ++rg) {
        f16x4 v;
        #pragma unroll
        for (int q = 0; q < 4; ++q) v[q] = (f16)fmaxf(acc[rg*4+q], 0.f);
        *(f16x4*)&hb[swzofs(32*wr + lr, 32*wc + 8*rg + 4*lh)] = v;
    }
    __syncthreads();

    #pragma unroll
    for (int rg = 0; rg < 4; ++rg) {
        const float4 bv = *(const float4*)(bi2 + 32*wc + 8*rg + 4*lh);
        acc[rg*4+0]=bv.x; acc[rg*4+1]=bv.y; acc[rg*4+2]=bv.z; acc[rg*4+3]=bv.w;
    }
    #pragma unroll
    for (int kt = 0; kt < 8; ++kt) {
        const f16x8 wf = load_wfrag<PRE>(WB+OFF_WI2, Wi2, 128, 4, kt, wc, l);
        const f16x8 af = lds_af(hb, 32*wr, 0, kt, l);
        acc = __builtin_amdgcn_mfma_f32_32x32x16_f16(wf, af, acc, 0, 0, 0);
    }

    float s[16];
    #pragma unroll
    for (int r = 0; r < 16; ++r) s[r] = rv ? __expf(acc[r]) : 0.0f;
    #pragma unroll
    for (int r = 0; r < 16; ++r) {
        float v = s[r];
        v += __shfl_xor(v, 1); v += __shfl_xor(v, 2);
        v += __shfl_xor(v, 4); v += __shfl_xor(v, 8); v += __shfl_xor(v, 16);
        if (lr == 0) atomicAdd(&sums[b*128 + 32*wc + 8*(r>>2) + 4*lh + (r&3)], v);
    }
}

template<bool PRE>
__global__ __launch_bounds__(512, 4)
void full_kernel(const float* __restrict__ x, const unsigned char* __restrict__ mask,
                 const float* __restrict__ Wi1, const float* __restrict__ bi1,
                 const float* __restrict__ Wi2, const float* __restrict__ bi2,
                 const float* __restrict__ We,
                 const float* __restrict__ Wo1, const float* __restrict__ bo1,
                 const float* __restrict__ Wo2, const float* __restrict__ bo2,
                 const float* __restrict__ sums, const f16* __restrict__ WB,
                 float* __restrict__ out)
{
    const int tid = threadIdx.x;
    const int l = tid & 63, w = tid >> 6, lr = l & 31, lh = l >> 5;
    const int wr = w >> 2, wc = w & 3;
    const int b = blockIdx.x / BPB;
    const int e0 = (blockIdx.x % BPB) * ROWS;

    __shared__ __align__(16) f16 hb[ROWS*256];
    __shared__ float red[8][64];
    __shared__ unsigned char mlds[Nn];

    if (tid < Nn) mlds[tid] = mask[b*Nn + tid];

    #pragma unroll
    for (int p = 0; p < 4; ++p) {
        const int row = p*32 + (tid >> 4);
        const int c0  = (tid & 15)*8;
        const long base = ((long)(b*NCUBE + e0 + row))*128 + c0;
        const float4 x0 = *(const float4*)&x[base];
        const float4 x1 = *(const float4*)&x[base + 4];
        f16x8 v; v[0]=(f16)x0.x; v[1]=(f16)x0.y; v[2]=(f16)x0.z; v[3]=(f16)x0.w;
                 v[4]=(f16)x1.x; v[5]=(f16)x1.y; v[6]=(f16)x1.z; v[7]=(f16)x1.w;
        *(f16x8*)&hb[swzofs(row, 128 + c0)] = v;
    }
    __syncthreads();

    bool valid[2];
    #pragma unroll
    for (int mt = 0; mt < 2; ++mt)
        valid[mt] = row_valid(e0 + 64*wr + 32*mt + lr, mlds);

    {
        f32x16 acc1[2];
        #pragma unroll
        for (int rg = 0; rg < 4; ++rg) {
            const float4 bv = *(const float4*)(bi1 + 32*wc + 8*rg + 4*lh);
            #pragma unroll
            for (int mt = 0; mt < 2; ++mt) {
                acc1[mt][rg*4+0]=bv.x; acc1[mt][rg*4+1]=bv.y;
                acc1[mt][rg*4+2]=bv.z; acc1[mt][rg*4+3]=bv.w;
            }
        }
        #pragma unroll
        for (int kt = 0; kt < 8; ++kt) {
            const f16x8 wf = load_wfrag<PRE>(WB+OFF_WI1, Wi1, 128, 4, kt, wc, l);
            #pragma unroll
            for (int mt = 0; mt < 2; ++mt) {
                const f16x8 af = lds_af(hb, 64*wr + 32*mt, 16, kt, l);
                acc1[mt] = __builtin_amdgcn_mfma_f32_32x32x16_f16(wf, af, acc1[mt], 0, 0, 0);
            }
        }
        #pragma unroll
        for (int mt = 0; mt < 2; ++mt)
            #pragma unroll
            for (int rg = 0; rg < 4; ++rg) {
                f16x4 v;
                #pragma unroll
                for (int q = 0; q < 4; ++q) v[q] = (f16)fmaxf(acc1[mt][rg*4+q], 0.f);
                *(f16x4*)&hb[swzofs(64*wr + 32*mt + lr, 32*wc + 8*rg + 4*lh)] = v;
            }
    }
    __syncthreads();

    f32x16 acc2[2];
    {
        #pragma unroll
        for (int rg = 0; rg < 4; ++rg) {
            const float4 bv = *(const float4*)(bi2 + 32*wc + 8*rg + 4*lh);
            #pragma unroll
            for (int mt = 0; mt < 2; ++mt) {
                acc2[mt][rg*4+0]=bv.x; acc2[mt][rg*4+1]=bv.y;
                acc2[mt][rg*4+2]=bv.z; acc2[mt][rg*4+3]=bv.w;
            }
        }
        #pragma unroll
        for (int kt = 0; kt < 8; ++kt) {
            const f16x8 wf = load_wfrag<PRE>(WB+OFF_WI2, Wi2, 128, 4, kt, wc, l);
            #pragma unroll
            for (int mt = 0; mt < 2; ++mt) {
                const f16x8 af = lds_af(hb, 64*wr + 32*mt, 0, kt, l);
                acc2[mt] = __builtin_amdgcn_mfma_f32_32x32x16_f16(wf, af, acc2[mt], 0, 0, 0);
            }
        }
        #pragma unroll
        for (int mt = 0; mt < 2; ++mt)
            #pragma unroll
            for (int rg = 0; rg < 4; ++rg) {
                f16x4 v;
                #pragma unroll
                for (int q = 0; q < 4; ++q) v[q] = (f16)acc2[mt][rg*4+q];
                *(f16x4*)&hb[swzofs(64*wr + 32*mt + lr, 128 + 32*wc + 8*rg + 4*lh)] = v;
            }
        #pragma unroll
        for (int rg = 0; rg < 4; ++rg) {
            const float4 sv = *(const float4*)(sums + b*128 + 32*wc + 8*rg + 4*lh);
            const float rinv[4] = {1.f/sv.x, 1.f/sv.y, 1.f/sv.z, 1.f/sv.w};
            #pragma unroll
            for (int mt = 0; mt < 2; ++mt)
                #pragma unroll
                for (int q = 0; q < 4; ++q)
                    acc2[mt][rg*4+q] = valid[mt] ? __expf(acc2[mt][rg*4+q]) * rinv[q] : 0.0f;
        }
    }
    __syncthreads();

    {
        f32x16 acc3[2];
        #pragma unroll
        for (int mt = 0; mt < 2; ++mt)
            #pragma unroll
            for (int r = 0; r < 16; ++r) acc3[mt][r] = 0.f;
        #pragma unroll
        for (int kt = 0; kt < 8; ++kt) {
            const f16x8 wf = load_wfrag<PRE>(WB+OFF_WE, We, 128, 4, kt, wc, l);
            #pragma unroll
            for (int mt = 0; mt < 2; ++mt) {
                const f16x8 af = lds_af(hb, 64*wr + 32*mt, 16, kt, l);
                acc3[mt] = __builtin_amdgcn_mfma_f32_32x32x16_f16(wf, af, acc3[mt], 0, 0, 0);
            }
        }
        #pragma unroll
        for (int mt = 0; mt < 2; ++mt)
            #pragma unroll
            for (int rg = 0; rg < 4; ++rg) {
                f16x4 v;
                #pragma unroll
                for (int q = 0; q < 4; ++q)
                    v[q] = (f16)(acc2[mt][rg*4+q] * fmaxf(acc3[mt][rg*4+q], 0.f));
                *(f16x4*)&hb[swzofs(64*wr + 32*mt + lr, 32*wc + 8*rg + 4*lh)] = v;
            }
    }
    __syncthreads();

    f32x16 acc4[2][2];
    #pragma unroll
    for (int ntl = 0; ntl < 2; ++ntl)
        #pragma unroll
        for (int rg = 0; rg < 4; ++rg) {
            const float4 bv = *(const float4*)(bo1 + 64*wc + 32*ntl + 8*rg + 4*lh);
            #pragma unroll
            for (int mt = 0; mt < 2; ++mt) {
                acc4[mt][ntl][rg*4+0]=bv.x; acc4[mt][ntl][rg*4+1]=bv.y;
                acc4[mt][ntl][rg*4+2]=bv.z; acc4[mt][ntl][rg*4+3]=bv.w;
            }
        }
    #pragma unroll
    for (int kt = 0; kt < 16; ++kt) {
        f16x8 of0 = load_wfrag<PRE>(WB+OFF_WO1, Wo1, 256, 8, kt, 2*wc+0, l);
        f16x8 of1 = load_wfrag<PRE>(WB+OFF_WO1, Wo1, 256, 8, kt, 2*wc+1, l);
        #pragma unroll
        for (int mt = 0; mt < 2; ++mt) {
            const f16x8 af = lds_af(hb, 64*wr + 32*mt, 0, kt, l);
            acc4[mt][0] = __builtin_amdgcn_mfma_f32_32x32x16_f16(of0, af, acc4[mt][0], 0, 0, 0);
            acc4[mt][1] = __builtin_amdgcn_mfma_f32_32x32x16_f16(of1, af, acc4[mt][1], 0, 0, 0);
        }
    }

    {
        float outp[2] = {0.f, 0.f};
        #pragma unroll
        for (int ntl = 0; ntl < 2; ++ntl)
            #pragma unroll
            for (int rg = 0; rg < 4; ++rg) {
                const float4 wv = *(const float4*)(Wo2 + 64*wc + 32*ntl + 8*rg + 4*lh);
                #pragma unroll
                for (int mt = 0; mt < 2; ++mt) {
                    outp[mt] += fmaxf(acc4[mt][ntl][rg*4+0], 0.f)*wv.x
                              + fmaxf(acc4[mt][ntl][rg*4+1], 0.f)*wv.y
                              + fmaxf(acc4[mt][ntl][rg*4+2], 0.f)*wv.z
                              + fmaxf(acc4[mt][ntl][rg*4+3], 0.f)*wv.w;
                }
            }
        #pragma unroll
        for (int mt = 0; mt < 2; ++mt) outp[mt] += __shfl_xor(outp[mt], 32);
        if (l < 32) {
            red[w][lr]      = outp[0];
            red[w][32 + lr] = outp[1];
        }
        __syncthreads();
        if (tid < ROWS) {
            const int wr2 = tid >> 6, idx = tid & 63;
            out[(long)b*NCUBE + e0 + tid] =
                red[wr2*4+0][idx] + red[wr2*4+1][idx] +
                red[wr2*4+2][idx] + red[wr2*4+3][idx] + bo2[0];
        }
    }
}

extern "C" void kernel_launch(void* const* d_in, const int* in_sizes, int n_in,
                              void* d_out, int out_size, void* d_ws, size_t ws_size,
                              hipStream_t stream) {
    const float*         x    = (const float*)d_in[0];
    const unsigned char* mask = (const unsigned char*)d_in[1];
    const float* Wi1 = (const float*)d_in[2];
    const float* bi1 = (const float*)d_in[3];
    const float* Wi2 = (const float*)d_in[4];
    const float* bi2 = (const float*)d_in[5];
    const float* We  = (const float*)d_in[6];
    const float* Wo1 = (const float*)d_in[7];
    const float* bo1 = (const float*)d_in[8];
    const float* Wo2 = (const float*)d_in[9];
    const float* bo2 = (const float*)d_in[10];
    float* out  = (float*)d_out;
    float* sums = (float*)d_ws;

    if (ws_size >= (size_t)WS_BIG) {
        float* psums = (float*)((char*)d_ws + 2048);
        f16*   xfg   = (f16*)((char*)d_ws + XFOFF_BIG);
        f16*   WB    = (f16*)((char*)d_ws + WBOFF_BIG);
        prep_kernel<<<56, 256, 0, stream>>>(Wi1, Wi2, We, Wo1, WB);
        embed_kernel<true><<<Bn*SBPB, 512, 0, stream>>>(x, mask, Wi1, bi1, Wi2, bi2,
                                                        psums, xfg, WB);
        sumreduce_kernel<<<Bn, 512, 0, stream>>>(psums, sums);
        out_kernel<true><<<Bn*BPB, 512, 0, stream>>>(xfg, mask, We, Wo1, bo1, Wo2, bo2,
                                                     sums, WB, out);
    } else if (ws_size >= (size_t)(WBOFF_SMALL + WB_BYTES)) {
        f16* WB = (f16*)((char*)d_ws + WBOFF_SMALL);
        hipMemsetAsync(d_ws, 0, 2048, stream);
        prep_kernel<<<56, 256, 0, stream>>>(Wi1, Wi2, We, Wo1, WB);
        sums_kernel<true><<<Bn*SBPB, 512, 0, stream>>>(x, mask, Wi1, bi1, Wi2, bi2, sums, WB);
        full_kernel<true><<<Bn*BPB, 512, 0, stream>>>(x, mask, Wi1, bi1, Wi2, bi2, We,
                                                      Wo1, bo1, Wo2, bo2, sums, WB, out);
    } else {
        hipMemsetAsync(d_ws, 0, 2048, stream);
        sums_kernel<false><<<Bn*SBPB, 512, 0, stream>>>(x, mask, Wi1, bi1, Wi2, bi2,
                                                        sums, nullptr);
        full_kernel<false><<<Bn*BPB, 512, 0, stream>>>(x, mask, Wi1, bi1, Wi2, bi2, We,
                                                       Wo1, bo1, Wo2, bo2, sums, nullptr, out);
    }
}

// Round 9
// 336.421 us; speedup vs baseline: 3.0341x; 1.0073x over previous
//
#include <hip/hip_runtime.h>

#define Bn 4
#define Nn 40
#define NCUBE 64000   // 40^3
#define ROWS 128      // rows per out/full tile
#define BPB  500      // out/full blocks per batch
#define SROWS 64      // rows per embed/sums tile
#define SBPB 1000     // embed/sums blocks per batch

typedef _Float16 f16;
typedef __attribute__((ext_vector_type(8)))  _Float16 f16x8;
typedef __attribute__((ext_vector_type(4)))  _Float16 f16x4;
typedef __attribute__((ext_vector_type(16))) float    f32x16;

// ---------------- workspace layout (bytes) ----------------
// BIG : 0 sums[Bn*128] | 2048 psums[Bn*SBPB*128] | xf[Bn*NCUBE*128 f16] | WB
// SMALL: 0 sums | 2560 WB
#define OFF_WI1 0
#define OFF_WI2 16384
#define OFF_WE  32768
#define OFF_WO1 49152
#define WB_HALFS 114688
#define WB_BYTES (WB_HALFS*2)
#define PS_BYTES (Bn*SBPB*128*4)           // 2,048,000
#define XF_BYTES (Bn*NCUBE*128*2)          // 65,536,000
#define XFOFF_BIG (2048 + PS_BYTES)
#define WBOFF_BIG (XFOFF_BIG + XF_BYTES)
#define WS_BIG    (WBOFF_BIG + WB_BYTES)
#define WBOFF_SMALL 2560

// 16B-granule XOR swizzle for [rows][256]-f16 LDS tiles (f16 units).
__device__ __forceinline__ int swz8(int row, int colg) {
    return row*256 + (((colg & ~7) | ((colg ^ row) & 7)) << 3);
}
__device__ __forceinline__ int swzofs(int row, int col) {
    return swz8(row, col >> 3) + (col & 7);
}

// Weight A-fragment for mfma_f32_32x32x16_f16 with SWAPPED operands
// (arg0 = W-frag): lane l, j holds W[kt*16 + 8*(l>>5) + j][nt*32 + (l&31)].
// D maps: chan = nt*32 + (reg&3)+8*(reg>>2)+4*(l>>5), act_row = base + (l&31).
template<bool PRE>
__device__ __forceinline__ f16x8 load_wfrag(const f16* __restrict__ WF,
                                            const float* __restrict__ W,
                                            int N, int NT, int kt, int nt, int l) {
    if constexpr (PRE) {
        return *(const f16x8*)(WF + ((kt*NT + nt)*64 + l)*8);
    } else {
        const int col = nt*32 + (l & 31);
        const int k0  = kt*16 + 8*(l >> 5);
        f16x8 r;
        #pragma unroll
        for (int j = 0; j < 8; ++j) r[j] = (f16)W[(k0 + j)*N + col];
        return r;
    }
}

// Activation B-fragment via swizzled ds_read_b128.
__device__ __forceinline__ f16x8 lds_af(const f16* hb, int rowbase, int areag, int kt, int l) {
    return *(const f16x8*)&hb[swz8(rowbase + (l & 31), areag + 2*kt + (l >> 5))];
}

__device__ __forceinline__ bool row_valid(int e, const unsigned char* mlds) {
    int k = e % Nn, ij = e / Nn, j = ij % Nn, i = ij / Nn;
    return (i < j) && (j < k) && mlds[i] && mlds[j] && mlds[k];
}

// ---------------------------------------------------------------------------
// One-time weight conversion into A-fragment layout (f16).
// ---------------------------------------------------------------------------
__global__ __launch_bounds__(256)
void prep_kernel(const float* __restrict__ Wi1, const float* __restrict__ Wi2,
                 const float* __restrict__ We,  const float* __restrict__ Wo1,
                 f16* __restrict__ WB) {
    int id = blockIdx.x*256 + threadIdx.x;   // 0..14335
    const float* W; int NT, N; f16* WF; int fid;
    if (id < 2048)      { W = Wi1; NT = 4; N = 128; WF = WB+OFF_WI1; fid = id; }
    else if (id < 4096) { W = Wi2; NT = 4; N = 128; WF = WB+OFF_WI2; fid = id-2048; }
    else if (id < 6144) { W = We;  NT = 4; N = 128; WF = WB+OFF_WE;  fid = id-4096; }
    else                { W = Wo1; NT = 8; N = 256; WF = WB+OFF_WO1; fid = id-6144; }
    int frag = fid >> 6, l = fid & 63;
    int nt = frag % NT, kt = frag / NT;
    int col = nt*32 + (l & 31), k0 = kt*16 + 8*(l >> 5);
    #pragma unroll
    for (int j = 0; j < 8; ++j) WF[frag*512 + l*8 + j] = (f16)W[(k0 + j)*N + col];
}

// ---------------------------------------------------------------------------
// K1 "embed": stages 1-2 for ALL rows; writes xf (f16) + per-block partial
// exp-sums (block-reduced, no global atomics — R7 lesson).
// 256 threads = 4 waves; wave w owns cols [32w,32w+32) for ALL 64 rows
// (mt=2): zero W duplication across waves + 2 independent MFMA chains.
// ---------------------------------------------------------------------------
template<bool PRE>
__global__ __launch_bounds__(256, 4)
void embed_kernel(const float* __restrict__ x, const unsigned char* __restrict__ mask,
                  const float* __restrict__ Wi1, const float* __restrict__ bi1,
                  const float* __restrict__ Wi2, const float* __restrict__ bi2,
                  float* __restrict__ psums, f16* __restrict__ xfg,
                  const f16* __restrict__ WB)
{
    const int tid = threadIdx.x;
    const int l = tid & 63, w = tid >> 6, lr = l & 31, lh = l >> 5;
    const int b   = blockIdx.x / SBPB;
    const int blk = blockIdx.x % SBPB;
    const int e0  = blk * SROWS;

    __shared__ __align__(16) f16 hb[SROWS*256];   // 32 KB
    __shared__ float sred[128];
    __shared__ unsigned char mlds[Nn];

    if (tid < Nn) mlds[tid] = mask[b*Nn + tid];

    // phA: x tile -> f16 LDS cols [128,256). 4 iters x 16 rows.
    #pragma unroll
    for (int p = 0; p < 4; ++p) {
        const int row = p*16 + (tid >> 4);
        const int c0  = (tid & 15)*8;
        const long base = ((long)(b*NCUBE + e0 + row))*128 + c0;
        const float4 x0 = *(const float4*)&x[base];
        const float4 x1 = *(const float4*)&x[base + 4];
        f16x8 v; v[0]=(f16)x0.x; v[1]=(f16)x0.y; v[2]=(f16)x0.z; v[3]=(f16)x0.w;
                 v[4]=(f16)x1.x; v[5]=(f16)x1.y; v[6]=(f16)x1.z; v[7]=(f16)x1.w;
        *(f16x8*)&hb[swzofs(row, 128 + c0)] = v;
    }
    __syncthreads();

    bool rv[2];
    #pragma unroll
    for (int mt = 0; mt < 2; ++mt)
        rv[mt] = row_valid(e0 + 32*mt + lr, mlds);

    // stage 1: h1 = relu(x @ Wi1 + bi1) -> cols [0,128). W hoisted, mt=2 ILP.
    f32x16 acc[2];
    {
        f16x8 wfr[8];
        #pragma unroll
        for (int kt = 0; kt < 8; ++kt)
            wfr[kt] = load_wfrag<PRE>(WB+OFF_WI1, Wi1, 128, 4, kt, w, l);
        #pragma unroll
        for (int rg = 0; rg < 4; ++rg) {
            const float4 bv = *(const float4*)(bi1 + 32*w + 8*rg + 4*lh);
            #pragma unroll
            for (int mt = 0; mt < 2; ++mt) {
                acc[mt][rg*4+0]=bv.x; acc[mt][rg*4+1]=bv.y;
                acc[mt][rg*4+2]=bv.z; acc[mt][rg*4+3]=bv.w;
            }
        }
        #pragma unroll
        for (int kt = 0; kt < 8; ++kt)
            #pragma unroll
            for (int mt = 0; mt < 2; ++mt) {
                const f16x8 af = lds_af(hb, 32*mt, 16, kt, l);
                acc[mt] = __builtin_amdgcn_mfma_f32_32x32x16_f16(wfr[kt], af, acc[mt], 0, 0, 0);
            }
        #pragma unroll
        for (int mt = 0; mt < 2; ++mt)
            #pragma unroll
            for (int rg = 0; rg < 4; ++rg) {
                f16x4 v;
                #pragma unroll
                for (int q = 0; q < 4; ++q) v[q] = (f16)fmaxf(acc[mt][rg*4+q], 0.f);
                *(f16x4*)&hb[swzofs(32*mt + lr, 32*w + 8*rg + 4*lh)] = v;
            }
    }
    __syncthreads();

    // stage 2: xf = h1 @ Wi2 + bi2. W hoisted, mt=2 ILP.
    {
        f16x8 wfr[8];
        #pragma unroll
        for (int kt = 0; kt < 8; ++kt)
            wfr[kt] = load_wfrag<PRE>(WB+OFF_WI2, Wi2, 128, 4, kt, w, l);
        #pragma unroll
        for (int rg = 0; rg < 4; ++rg) {
            const float4 bv = *(const float4*)(bi2 + 32*w + 8*rg + 4*lh);
            #pragma unroll
            for (int mt = 0; mt < 2; ++mt) {
                acc[mt][rg*4+0]=bv.x; acc[mt][rg*4+1]=bv.y;
                acc[mt][rg*4+2]=bv.z; acc[mt][rg*4+3]=bv.w;
            }
        }
        #pragma unroll
        for (int kt = 0; kt < 8; ++kt)
            #pragma unroll
            for (int mt = 0; mt < 2; ++mt) {
                const f16x8 af = lds_af(hb, 32*mt, 0, kt, l);
                acc[mt] = __builtin_amdgcn_mfma_f32_32x32x16_f16(wfr[kt], af, acc[mt], 0, 0, 0);
            }
    }

    // round xf to f16 -> cols [128,256); masked exp of SAME f16 values,
    // mt-pair summed in-thread BEFORE the 5-step butterfly (halved shuffles).
    float s[16];
    #pragma unroll
    for (int r = 0; r < 16; ++r) s[r] = 0.f;
    #pragma unroll
    for (int mt = 0; mt < 2; ++mt)
        #pragma unroll
        for (int rg = 0; rg < 4; ++rg) {
            f16x4 v;
            #pragma unroll
            for (int q = 0; q < 4; ++q) {
                v[q] = (f16)acc[mt][rg*4+q];
                if (rv[mt]) s[rg*4+q] += __expf((float)v[q]);
            }
            *(f16x4*)&hb[swzofs(32*mt + lr, 128 + 32*w + 8*rg + 4*lh)] = v;
        }
    #pragma unroll
    for (int r = 0; r < 16; ++r) {
        float v = s[r];
        v += __shfl_xor(v, 1); v += __shfl_xor(v, 2);
        v += __shfl_xor(v, 4); v += __shfl_xor(v, 8); v += __shfl_xor(v, 16);
        s[r] = v;
    }
    if (lr == 0) {
        #pragma unroll
        for (int r = 0; r < 16; ++r)
            sred[32*w + 8*(r>>2) + 4*lh + (r&3)] = s[r];   // waves own distinct cols
    }
    __syncthreads();
    if (tid < 128)
        psums[((long)(b*SBPB + blk))*128 + tid] = sred[tid];

    // copy xf tile -> global (coalesced 16B/lane)
    #pragma unroll
    for (int p = 0; p < 4; ++p) {
        const int row = p*16 + (tid >> 4);
        const int c0  = (tid & 15)*8;
        const f16x8 v = *(const f16x8*)&hb[swzofs(row, 128 + c0)];
        *(f16x8*)&xfg[((long)(b*NCUBE + e0 + row))*128 + c0] = v;
    }
}

// ---------------------------------------------------------------------------
// Reduce psums (Bn x SBPB x 128) -> sums (Bn x 128). One block per batch.
// ---------------------------------------------------------------------------
__global__ __launch_bounds__(512)
void sumreduce_kernel(const float* __restrict__ psums, float* __restrict__ sums) {
    const int b = blockIdx.x;
    const int c = threadIdx.x & 127, q = threadIdx.x >> 7;
    float s = 0.f;
    for (int g = q; g < SBPB; g += 4)
        s += psums[((long)(b*SBPB + g))*128 + c];
    __shared__ float tmp[4][128];
    tmp[q][c] = s;
    __syncthreads();
    if (q == 0) sums[b*128 + c] = tmp[0][c] + tmp[1][c] + tmp[2][c] + tmp[3][c];
}

// ---------------------------------------------------------------------------
// K2 "out": loads xf, computes s3 (xi), a = valid?exp(xf)/sum:0, s4, s5.
// 128-row tiles, 512 threads. s3: 8 waves = 2 wr x 4 wc (as before).
// s4: wave w owns nt=w (cols [32w,32w+32)) for ALL 128 rows (mt=4):
// halves s4's L2 W traffic, 4 independent acc chains.
// ---------------------------------------------------------------------------
template<bool PRE>
__global__ __launch_bounds__(512, 4)
void out_kernel(const f16* __restrict__ xfg, const unsigned char* __restrict__ mask,
                const float* __restrict__ We,
                const float* __restrict__ Wo1, const float* __restrict__ bo1,
                const float* __restrict__ Wo2, const float* __restrict__ bo2,
                const float* __restrict__ sums, const f16* __restrict__ WB,
                float* __restrict__ out)
{
    const int tid = threadIdx.x;
    const int l = tid & 63, w = tid >> 6, lr = l & 31, lh = l >> 5;
    const int wr = w >> 2, wc = w & 3;
    const int b = blockIdx.x / BPB;
    const int e0 = (blockIdx.x % BPB) * ROWS;

    __shared__ __align__(16) f16 hb[ROWS*256];   // 64 KB
    __shared__ float red[8][128];
    __shared__ unsigned char mlds[Nn];

    if (tid < Nn) mlds[tid] = mask[b*Nn + tid];

    // phA: xf tile -> LDS cols [128,256)
    #pragma unroll
    for (int p = 0; p < 4; ++p) {
        const int row = p*32 + (tid >> 4);
        const int c0  = (tid & 15)*8;
        const f16x8 v = *(const f16x8*)&xfg[((long)(b*NCUBE + e0 + row))*128 + c0];
        *(f16x8*)&hb[swzofs(row, 128 + c0)] = v;
    }
    __syncthreads();

    bool valid[2];
    #pragma unroll
    for (int mt = 0; mt < 2; ++mt)
        valid[mt] = row_valid(e0 + 64*wr + 32*mt + lr, mlds);

    // ---- stage 3: xi = relu(xf @ We); a*xi -> cols [0,128). (wr,wc) layout. ----
    {
        f16x8 wfr[8];
        #pragma unroll
        for (int kt = 0; kt < 8; ++kt)
            wfr[kt] = load_wfrag<PRE>(WB+OFF_WE, We, 128, 4, kt, wc, l);
        f32x16 acc3[2];
        #pragma unroll
        for (int mt = 0; mt < 2; ++mt)
            #pragma unroll
            for (int r = 0; r < 16; ++r) acc3[mt][r] = 0.f;
        #pragma unroll
        for (int kt = 0; kt < 8; ++kt)
            #pragma unroll
            for (int mt = 0; mt < 2; ++mt) {
                const f16x8 af = lds_af(hb, 64*wr + 32*mt, 16, kt, l);
                acc3[mt] = __builtin_amdgcn_mfma_f32_32x32x16_f16(wfr[kt], af, acc3[mt], 0, 0, 0);
            }
        #pragma unroll
        for (int rg = 0; rg < 4; ++rg) {
            const float4 sv = *(const float4*)(sums + b*128 + 32*wc + 8*rg + 4*lh);
            const float rinv[4] = {1.f/sv.x, 1.f/sv.y, 1.f/sv.z, 1.f/sv.w};
            #pragma unroll
            for (int mt = 0; mt < 2; ++mt) {
                const f16x4 xq = *(const f16x4*)&hb[swzofs(64*wr + 32*mt + lr,
                                                           128 + 32*wc + 8*rg + 4*lh)];
                f16x4 v;
                #pragma unroll
                for (int q = 0; q < 4; ++q) {
                    const float aa = valid[mt] ? __expf((float)xq[q]) * rinv[q] : 0.0f;
                    v[q] = (f16)(aa * fmaxf(acc3[mt][rg*4+q], 0.f));
                }
                *(f16x4*)&hb[swzofs(64*wr + 32*mt + lr, 32*wc + 8*rg + 4*lh)] = v;
            }
        }
    }
    __syncthreads();

    // ---- stage 4: g = relu(h @ Wo1 + bo1), K=256. wave w = nt, mt=4. ----
    f32x16 acc4[4];
    #pragma unroll
    for (int rg = 0; rg < 4; ++rg) {
        const float4 bv = *(const float4*)(bo1 + 32*w + 8*rg + 4*lh);
        #pragma unroll
        for (int mt = 0; mt < 4; ++mt) {
            acc4[mt][rg*4+0]=bv.x; acc4[mt][rg*4+1]=bv.y;
            acc4[mt][rg*4+2]=bv.z; acc4[mt][rg*4+3]=bv.w;
        }
    }
    {
        f16x8 of = load_wfrag<PRE>(WB+OFF_WO1, Wo1, 256, 8, 0, w, l);
        #pragma unroll
        for (int kt = 0; kt < 16; ++kt) {
            f16x8 nf = of;
            if (kt < 15) nf = load_wfrag<PRE>(WB+OFF_WO1, Wo1, 256, 8, kt+1, w, l);
            #pragma unroll
            for (int mt = 0; mt < 4; ++mt) {
                const f16x8 af = lds_af(hb, 32*mt, 0, kt, l);
                acc4[mt] = __builtin_amdgcn_mfma_f32_32x32x16_f16(of, af, acc4[mt], 0, 0, 0);
            }
            of = nf;
        }
    }

    // ---- stage 5: out = relu(g) @ Wo2 + bo2, reduce 256 -> 1 per row ----
    {
        float outp[4] = {0.f, 0.f, 0.f, 0.f};
        #pragma unroll
        for (int rg = 0; rg < 4; ++rg) {
            const float4 wv = *(const float4*)(Wo2 + 32*w + 8*rg + 4*lh);
            #pragma unroll
            for (int mt = 0; mt < 4; ++mt) {
                outp[mt] += fmaxf(acc4[mt][rg*4+0], 0.f)*wv.x
                          + fmaxf(acc4[mt][rg*4+1], 0.f)*wv.y
                          + fmaxf(acc4[mt][rg*4+2], 0.f)*wv.z
                          + fmaxf(acc4[mt][rg*4+3], 0.f)*wv.w;
            }
        }
        #pragma unroll
        for (int mt = 0; mt < 4; ++mt) outp[mt] += __shfl_xor(outp[mt], 32);
        if (l < 32) {
            #pragma unroll
            for (int mt = 0; mt < 4; ++mt) red[w][32*mt + lr] = outp[mt];
        }
        __syncthreads();
        if (tid < ROWS) {
            out[(long)b*NCUBE + e0 + tid] =
                red[0][tid] + red[1][tid] + red[2][tid] + red[3][tid] +
                red[4][tid] + red[5][tid] + red[6][tid] + red[7][tid] + bo2[0];
        }
    }
}

// ---------------------------------------------------------------------------
// Fallback tier (ws too small for xf+psums): R6-style dense sums + full.
// ---------------------------------------------------------------------------
template<bool PRE>
__global__ __launch_bounds__(512, 4)
void sums_kernel(const float* __restrict__ x, const unsigned char* __restrict__ mask,
                 const float* __restrict__ Wi1, const float* __restrict__ bi1,
                 const float* __restrict__ Wi2, const float* __restrict__ bi2,
                 float* __restrict__ sums, const f16* __restrict__ WB)
{
    const int tid = threadIdx.x;
    const int l = tid & 63, w = tid >> 6, lr = l & 31, lh = l >> 5;
    const int wr = w >> 2, wc = w & 3;
    const int b = blockIdx.x / SBPB;
    const int e0 = (blockIdx.x % SBPB) * SROWS;

    __shared__ __align__(16) f16 hb[SROWS*256];
    __shared__ unsigned char mlds[Nn];
    __shared__ int anyv;

    if (tid < Nn) mlds[tid] = mask[b*Nn + tid];
    if (tid == 0) anyv = 0;
    __syncthreads();

    const bool rv = row_valid(e0 + 32*wr + lr, mlds);
    if (__any(rv)) anyv = 1;
    __syncthreads();
    if (!anyv) return;

    #pragma unroll
    for (int p = 0; p < 2; ++p) {
        const int row = p*32 + (tid >> 4);
        const int c0  = (tid & 15)*8;
        const long base = ((long)(b*NCUBE + e0 + row))*128 + c0;
        const float4 x0 = *(const float4*)&x[base];
        const float4 x1 = *(const float4*)&x[base + 4];
        f16x8 v; v[0]=(f16)x0.x; v[1]=(f16)x0.y; v[2]=(f16)x0.z; v[3]=(f16)x0.w;
                 v[4]=(f16)x1.x; v[5]=(f16)x1.y; v[6]=(f16)x1.z; v[7]=(f16)x1.w;
        *(f16x8*)&hb[swzofs(row, 128 + c0)] = v;
    }
    __syncthreads();

    f32x16 acc;
    #pragma unroll
    for (int rg = 0; rg < 4; ++rg) {
        const float4 bv = *(const float4*)(bi1 + 32*wc + 8*rg + 4*lh);
        acc[rg*4+0]=bv.x; acc[rg*4+1]=bv.y; acc[rg*4+2]=bv.z; acc[rg*4+3]=bv.w;
    }
    #pragma unroll
    for (int kt = 0; kt < 8; ++kt) {
        const f16x8 wf = load_wfrag<PRE>(WB+OFF_WI1, Wi1, 128, 4, kt, wc, l);
        const f16x8 af = lds_af(hb, 32*wr, 16, kt, l);
        acc = __builtin_amdgcn_mfma_f32_32x32x16_f16(wf, af, acc, 0, 0, 0);
    }
    #pragma unroll
    for (int rg = 0; rg < 4; ++rg) {
        f16x4 v;
        #pragma unroll
        for (int q = 0; q < 4; ++q) v[q] = (f16)fmaxf(acc[rg*4+q], 0.f);
        *(f16x4*)&hb[swzofs(32*wr + lr, 32*wc + 8*rg + 4*lh)] = v;
    }
    __syncthreads();

    #pragma unroll
    for (int rg = 0; rg < 4; ++rg) {
        const float4 bv = *(const float4*)(bi2 + 32*wc + 8*rg + 4*lh);
        acc[rg*4+0]=bv.x; acc[rg*4+1]=bv.y; acc[rg*4+2]=bv.z; acc[rg*4+3]=bv.w;
    }
    #pragma unroll
    for (int kt = 0; kt < 8; ++kt) {
        const f16x8 wf = load_wfrag<PRE>(WB+OFF_WI2, Wi2, 128, 4, kt, wc, l);
        const f16x8 af = lds_af(hb, 32*wr, 0, kt, l);
        acc = __builtin_amdgcn_mfma_f32_32x32x16_f16(wf, af, acc, 0, 0, 0);
    }

    float s[16];
    #pragma unroll
    for (int r = 0; r < 16; ++r) s[r] = rv ? __expf(acc[r]) : 0.0f;
    #pragma unroll
    for (int r = 0; r < 16; ++r) {
        float v = s[r];
        v += __shfl_xor(v, 1); v += __shfl_xor(v, 2);
        v += __shfl_xor(v, 4); v += __shfl_xor(v, 8); v += __shfl_xor(v, 16);
        if (lr == 0) atomicAdd(&sums[b*128 + 32*wc + 8*(r>>2) + 4*lh + (r&3)], v);
    }
}

template<bool PRE>
__global__ __launch_bounds__(512, 4)
void full_kernel(const float* __restrict__ x, const unsigned char* __restrict__ mask,
                 const float* __restrict__ Wi1, const float* __restrict__ bi1,
                 const float* __restrict__ Wi2, const float* __restrict__ bi2,
                 const float* __restrict__ We,
                 const float* __restrict__ Wo1, const float* __restrict__ bo1,
                 const float* __restrict__ Wo2, const float* __restrict__ bo2,
                 const float* __restrict__ sums, const f16* __restrict__ WB,
                 float* __restrict__ out)
{
    const int tid = threadIdx.x;
    const int l = tid & 63, w = tid >> 6, lr = l & 31, lh = l >> 5;
    const int wr = w >> 2, wc = w & 3;
    const int b = blockIdx.x / BPB;
    const int e0 = (blockIdx.x % BPB) * ROWS;

    __shared__ __align__(16) f16 hb[ROWS*256];
    __shared__ float red[8][64];
    __shared__ unsigned char mlds[Nn];

    if (tid < Nn) mlds[tid] = mask[b*Nn + tid];

    #pragma unroll
    for (int p = 0; p < 4; ++p) {
        const int row = p*32 + (tid >> 4);
        const int c0  = (tid & 15)*8;
        const long base = ((long)(b*NCUBE + e0 + row))*128 + c0;
        const float4 x0 = *(const float4*)&x[base];
        const float4 x1 = *(const float4*)&x[base + 4];
        f16x8 v; v[0]=(f16)x0.x; v[1]=(f16)x0.y; v[2]=(f16)x0.z; v[3]=(f16)x0.w;
                 v[4]=(f16)x1.x; v[5]=(f16)x1.y; v[6]=(f16)x1.z; v[7]=(f16)x1.w;
        *(f16x8*)&hb[swzofs(row, 128 + c0)] = v;
    }
    __syncthreads();

    bool valid[2];
    #pragma unroll
    for (int mt = 0; mt < 2; ++mt)
        valid[mt] = row_valid(e0 + 64*wr + 32*mt + lr, mlds);

    {
        f32x16 acc1[2];
        #pragma unroll
        for (int rg = 0; rg < 4; ++rg) {
            const float4 bv = *(const float4*)(bi1 + 32*wc + 8*rg + 4*lh);
            #pragma unroll
            for (int mt = 0; mt < 2; ++mt) {
                acc1[mt][rg*4+0]=bv.x; acc1[mt][rg*4+1]=bv.y;
                acc1[mt][rg*4+2]=bv.z; acc1[mt][rg*4+3]=bv.w;
            }
        }
        #pragma unroll
        for (int kt = 0; kt < 8; ++kt) {
            const f16x8 wf = load_wfrag<PRE>(WB+OFF_WI1, Wi1, 128, 4, kt, wc, l);
            #pragma unroll
            for (int mt = 0; mt < 2; ++mt) {
                const f16x8 af = lds_af(hb, 64*wr + 32*mt, 16, kt, l);
                acc1[mt] = __builtin_amdgcn_mfma_f32_32x32x16_f16(wf, af, acc1[mt], 0, 0, 0);
            }
        }
        #pragma unroll
        for (int mt = 0; mt < 2; ++mt)
            #pragma unroll
            for (int rg = 0; rg < 4; ++rg) {
                f16x4 v;
                #pragma unroll
                for (int q = 0; q < 4; ++q) v[q] = (f16)fmaxf(acc1[mt][rg*4+q], 0.f);
                *(f16x4*)&hb[swzofs(64*wr + 32*mt + lr, 32*wc + 8*rg + 4*lh)] = v;
            }
    }
    __syncthreads();

    f32x16 acc2[2];
    {
        #pragma unroll
        for (int rg = 0; rg < 4; ++rg) {
            const float4 bv = *(const float4*)(bi2 + 32*wc + 8*rg + 4*lh);
            #pragma unroll
            for (int mt = 0; mt < 2; ++mt) {
                acc2[mt][rg*4+0]=bv.x; acc2[mt][rg*4+1]=bv.y;
                acc2[mt][rg*4+2]=bv.z; acc2[mt][rg*4+3]=bv.w;
            }
        }
        #pragma unroll
        for (int kt = 0; kt < 8; ++kt) {
            const f16x8 wf = load_wfrag<PRE>(WB+OFF_WI2, Wi2, 128, 4, kt, wc, l);
            #pragma unroll
            for (int mt = 0; mt < 2; ++mt) {
                const f16x8 af = lds_af(hb, 64*wr + 32*mt, 0, kt, l);
                acc2[mt] = __builtin_amdgcn_mfma_f32_32x32x16_f16(wf, af, acc2[mt], 0, 0, 0);
            }
        }
        #pragma unroll
        for (int mt = 0; mt < 2; ++mt)
            #pragma unroll
            for (int rg = 0; rg < 4; ++rg) {
                f16x4 v;
                #pragma unroll
                for (int q = 0; q < 4; ++q) v[q] = (f16)acc2[mt][rg*4+q];
                *(f16x4*)&hb[swzofs(64*wr + 32*mt + lr, 128 + 32*wc + 8*rg + 4*lh)] = v;
            }
        #pragma unroll
        for (int rg = 0; rg < 4; ++rg) {
            const float4 sv = *(const float4*)(sums + b*128 + 32*wc + 8*rg + 4*lh);
            const float rinv[4] = {1.f/sv.x, 1.f/sv.y, 1.f/sv.z, 1.f/sv.w};
            #pragma unroll
            for (int mt = 0; mt < 2; ++mt)
                #pragma unroll
                for (int q = 0; q < 4; ++q)
                    acc2[mt][rg*4+q] = valid[mt] ? __expf(acc2[mt][rg*4+q]) * rinv[q] : 0.0f;
        }
    }
    __syncthreads();

    {
        f32x16 acc3[2];
        #pragma unroll
        for (int mt = 0; mt < 2; ++mt)
            #pragma unroll
            for (int r = 0; r < 16; ++r) acc3[mt][r] = 0.f;
        #pragma unroll
        for (int kt = 0; kt < 8; ++kt) {
            const f16x8 wf = load_wfrag<PRE>(WB+OFF_WE, We, 128, 4, kt, wc, l);
            #pragma unroll
            for (int mt = 0; mt < 2; ++mt) {
                const f16x8 af = lds_af(hb, 64*wr + 32*mt, 16, kt, l);
                acc3[mt] = __builtin_amdgcn_mfma_f32_32x32x16_f16(wf, af, acc3[mt], 0, 0, 0);
            }
        }
        #pragma unroll
        for (int mt = 0; mt < 2; ++mt)
            #pragma unroll
            for (int rg = 0; rg < 4; ++rg) {
                f16x4 v;
                #pragma unroll
                for (int q = 0; q < 4; ++q)
                    v[q] = (f16)(acc2[mt][rg*4+q] * fmaxf(acc3[mt][rg*4+q], 0.f));
                *(f16x4*)&hb[swzofs(64*wr + 32*mt + lr, 32*wc + 8*rg + 4*lh)] = v;
            }
    }
    __syncthreads();

    f32x16 acc4[2][2];
    #pragma unroll
    for (int ntl = 0; ntl < 2; ++ntl)
        #pragma unroll
        for (int rg = 0; rg < 4; ++rg) {
            const float4 bv = *(const float4*)(bo1 + 64*wc + 32*ntl + 8*rg + 4*lh);
            #pragma unroll
            for (int mt = 0; mt < 2; ++mt) {
                acc4[mt][ntl][rg*4+0]=bv.x; acc4[mt][ntl][rg*4+1]=bv.y;
                acc4[mt][ntl][rg*4+2]=bv.z; acc4[mt][ntl][rg*4+3]=bv.w;
            }
        }
    #pragma unroll
    for (int kt = 0; kt < 16; ++kt) {
        f16x8 of0 = load_wfrag<PRE>(WB+OFF_WO1, Wo1, 256, 8, kt, 2*wc+0, l);
        f16x8 of1 = load_wfrag<PRE>(WB+OFF_WO1, Wo1, 256, 8, kt, 2*wc+1, l);
        #pragma unroll
        for (int mt = 0; mt < 2; ++mt) {
            const f16x8 af = lds_af(hb, 64*wr + 32*mt, 0, kt, l);
            acc4[mt][0] = __builtin_amdgcn_mfma_f32_32x32x16_f16(of0, af, acc4[mt][0], 0, 0, 0);
            acc4[mt][1] = __builtin_amdgcn_mfma_f32_32x32x16_f16(of1, af, acc4[mt][1], 0, 0, 0);
        }
    }

    {
        float outp[2] = {0.f, 0.f};
        #pragma unroll
        for (int ntl = 0; ntl < 2; ++ntl)
            #pragma unroll
            for (int rg = 0; rg < 4; ++rg) {
                const float4 wv = *(const float4*)(Wo2 + 64*wc + 32*ntl + 8*rg + 4*lh);
                #pragma unroll
                for (int mt = 0; mt < 2; ++mt) {
                    outp[mt] += fmaxf(acc4[mt][ntl][rg*4+0], 0.f)*wv.x
                              + fmaxf(acc4[mt][ntl][rg*4+1], 0.f)*wv.y
                              + fmaxf(acc4[mt][ntl][rg*4+2], 0.f)*wv.z
                              + fmaxf(acc4[mt][ntl][rg*4+3], 0.f)*wv.w;
                }
            }
        #pragma unroll
        for (int mt = 0; mt < 2; ++mt) outp[mt] += __shfl_xor(outp[mt], 32);
        if (l < 32) {
            red[w][lr]      = outp[0];
            red[w][32 + lr] = outp[1];
        }
        __syncthreads();
        if (tid < ROWS) {
            const int wr2 = tid >> 6, idx = tid & 63;
            out[(long)b*NCUBE + e0 + tid] =
                red[wr2*4+0][idx] + red[wr2*4+1][idx] +
                red[wr2*4+2][idx] + red[wr2*4+3][idx] + bo2[0];
        }
    }
}

extern "C" void kernel_launch(void* const* d_in, const int* in_sizes, int n_in,
                              void* d_out, int out_size, void* d_ws, size_t ws_size,
                              hipStream_t stream) {
    const float*         x    = (const float*)d_in[0];
    const unsigned char* mask = (const unsigned char*)d_in[1];
    const float* Wi1 = (const float*)d_in[2];
    const float* bi1 = (const float*)d_in[3];
    const float* Wi2 = (const float*)d_in[4];
    const float* bi2 = (const float*)d_in[5];
    const float* We  = (const float*)d_in[6];
    const float* Wo1 = (const float*)d_in[7];
    const float* bo1 = (const float*)d_in[8];
    const float* Wo2 = (const float*)d_in[9];
    const float* bo2 = (const float*)d_in[10];
    float* out  = (float*)d_out;
    float* sums = (float*)d_ws;

    if (ws_size >= (size_t)WS_BIG) {
        float* psums = (float*)((char*)d_ws + 2048);
        f16*   xfg   = (f16*)((char*)d_ws + XFOFF_BIG);
        f16*   WB    = (f16*)((char*)d_ws + WBOFF_BIG);
        prep_kernel<<<56, 256, 0, stream>>>(Wi1, Wi2, We, Wo1, WB);
        embed_kernel<true><<<Bn*SBPB, 256, 0, stream>>>(x, mask, Wi1, bi1, Wi2, bi2,
                                                        psums, xfg, WB);
        sumreduce_kernel<<<Bn, 512, 0, stream>>>(psums, sums);
        out_kernel<true><<<Bn*BPB, 512, 0, stream>>>(xfg, mask, We, Wo1, bo1, Wo2, bo2,
                                                     sums, WB, out);
    } else if (ws_size >= (size_t)(WBOFF_SMALL + WB_BYTES)) {
        f16* WB = (f16*)((char*)d_ws + WBOFF_SMALL);
        hipMemsetAsync(d_ws, 0, 2048, stream);
        prep_kernel<<<56, 256, 0, stream>>>(Wi1, Wi2, We, Wo1, WB);
        sums_kernel<true><<<Bn*SBPB, 512, 0, stream>>>(x, mask, Wi1, bi1, Wi2, bi2, sums, WB);
        full_kernel<true><<<Bn*BPB, 512, 0, stream>>>(x, mask, Wi1, bi1, Wi2, bi2, We,
                                                      Wo1, bo1, Wo2, bo2, sums, WB, out);
    } else {
        hipMemsetAsync(d_ws, 0, 2048, stream);
        sums_kernel<false><<<Bn*SBPB, 512, 0, stream>>>(x, mask, Wi1, bi1, Wi2, bi2,
                                                        sums, nullptr);
        full_kernel<false><<<Bn*BPB, 512, 0, stream>>>(x, mask, Wi1, bi1, Wi2, bi2, We,
                                                       Wo1, bo1, Wo2, bo2, sums, nullptr, out);
    }
}

// Round 10
// 261.646 us; speedup vs baseline: 3.9012x; 1.2858x over previous
//
#include <hip/hip_runtime.h>

#define Bn 4
#define Nn 40
#define NCUBE 64000   // 40^3
#define ROWS 128      // rows per full tile
#define BPB  500      // full blocks per batch
#define SROWS 64      // rows per sums tile
#define SBPB 1000     // dense-sums blocks per batch
#define MAXV 16384    // valid-row list capacity (>= C(40,3)=9880)
#define CBLK 160      // compact-sums blocks per batch

typedef _Float16 f16;
typedef __attribute__((ext_vector_type(8)))  _Float16 f16x8;
typedef __attribute__((ext_vector_type(4)))  _Float16 f16x4;
typedef __attribute__((ext_vector_type(16))) float    f32x16;

// ---------------- workspace layout (bytes) ----------------
// 0      : sums[Bn*128] f32
// 2048   : cnt[Bn] int
// 4096   : vlist[Bn*MAXV] int        (compact tier only)
// WBOFF  : f16 weight A-fragments (offsets below in halfs)
#define OFF_WI1 0
#define OFF_WI2 16384
#define OFF_WE  32768
#define OFF_WO1 49152
#define WB_HALFS 114688
#define WB_BYTES (WB_HALFS*2)
#define WBOFF_COMPACT (4096 + Bn*MAXV*4)   // 266240
#define WBOFF_SMALL   2560

// 16B-granule XOR swizzle for [rows][256]-f16 LDS tiles (f16 units).
__device__ __forceinline__ int swz8(int row, int colg) {
    return row*256 + (((colg & ~7) | ((colg ^ row) & 7)) << 3);
}
__device__ __forceinline__ int swzofs(int row, int col) {
    return swz8(row, col >> 3) + (col & 7);
}

// Weight A-fragment for mfma_f32_32x32x16_f16 with SWAPPED operands
// (arg0 = W-frag): lane l, j holds W[kt*16 + 8*(l>>5) + j][nt*32 + (l&31)].
// D maps: chan = nt*32 + (reg&3)+8*(reg>>2)+4*(l>>5), act_row = base + (l&31).
template<bool PRE>
__device__ __forceinline__ f16x8 load_wfrag(const f16* __restrict__ WF,
                                            const float* __restrict__ W,
                                            int N, int NT, int kt, int nt, int l) {
    if constexpr (PRE) {
        return *(const f16x8*)(WF + ((kt*NT + nt)*64 + l)*8);
    } else {
        const int col = nt*32 + (l & 31);
        const int k0  = kt*16 + 8*(l >> 5);
        f16x8 r;
        #pragma unroll
        for (int j = 0; j < 8; ++j) r[j] = (f16)W[(k0 + j)*N + col];
        return r;
    }
}

// Activation B-fragment via swizzled ds_read_b128.
__device__ __forceinline__ f16x8 lds_af(const f16* hb, int rowbase, int areag, int kt, int l) {
    return *(const f16x8*)&hb[swz8(rowbase + (l & 31), areag + 2*kt + (l >> 5))];
}

__device__ __forceinline__ bool row_valid(int e, const unsigned char* mlds) {
    int k = e % Nn, ij = e / Nn, j = ij % Nn, i = ij / Nn;
    return (i < j) && (j < k) && mlds[i] && mlds[j] && mlds[k];
}

// ---------------------------------------------------------------------------
// One-time weight conversion into A-fragment layout + valid-row compaction.
// Blocks [0,56): prep.  Blocks [56,1056): ballot compaction.
// ---------------------------------------------------------------------------
__global__ __launch_bounds__(256)
void prepcount_kernel(const float* __restrict__ Wi1, const float* __restrict__ Wi2,
                      const float* __restrict__ We,  const float* __restrict__ Wo1,
                      f16* __restrict__ WB, const unsigned char* __restrict__ mask,
                      int* __restrict__ cnt, int* __restrict__ vlist) {
    const int blk = blockIdx.x;
    if (blk < 56) {
        int id = blk*256 + threadIdx.x;   // 0..14335
        const float* W; int NT, N; f16* WF; int fid;
        if (id < 2048)      { W = Wi1; NT = 4; N = 128; WF = WB+OFF_WI1; fid = id; }
        else if (id < 4096) { W = Wi2; NT = 4; N = 128; WF = WB+OFF_WI2; fid = id-2048; }
        else if (id < 6144) { W = We;  NT = 4; N = 128; WF = WB+OFF_WE;  fid = id-4096; }
        else                { W = Wo1; NT = 8; N = 256; WF = WB+OFF_WO1; fid = id-6144; }
        int frag = fid >> 6, l = fid & 63;
        int nt = frag % NT, kt = frag / NT;
        int col = nt*32 + (l & 31), k0 = kt*16 + 8*(l >> 5);
        #pragma unroll
        for (int j = 0; j < 8; ++j) WF[frag*512 + l*8 + j] = (f16)W[(k0 + j)*N + col];
    } else {
        const int idx = (blk - 56)*256 + threadIdx.x;   // 0..255999
        const int b = idx / NCUBE, e = idx % NCUBE;
        const int k = e % Nn, ij = e / Nn, j = ij % Nn, i = ij / Nn;
        const bool v = (i < j) && (j < k) &&
                       mask[b*Nn+i] && mask[b*Nn+j] && mask[b*Nn+k];
        const unsigned long long m = __ballot(v);
        const int lane = threadIdx.x & 63;
        const int c = __popcll(m);
        int base = 0;
        if (lane == 0 && c) base = atomicAdd(&cnt[b], c);
        base = __shfl(base, 0);
        if (v) vlist[b*MAXV + base + __popcll(m & ((1ull<<lane)-1ull))] = e;
    }
}

// ---------------------------------------------------------------------------
// Sums kernel: stages 1-2 + masked exp-sum over 64-row tiles. 8 waves =
// 2 row-groups (wr: 32 rows) x 4 col-slices (wc: 32 chans). 32x32x16 MFMA.
// COMPACT: rows gathered from vlist (~10K valid rows per batch -> ~640 blocks
// total; atomic count small, verified fine at R6).
// ---------------------------------------------------------------------------
template<bool PRE, bool COMPACT>
__global__ __launch_bounds__(512, 4)
void sums_kernel(const float* __restrict__ x, const unsigned char* __restrict__ mask,
                 const float* __restrict__ Wi1, const float* __restrict__ bi1,
                 const float* __restrict__ Wi2, const float* __restrict__ bi2,
                 float* __restrict__ sums, const int* __restrict__ cnt,
                 const int* __restrict__ vlist, const f16* __restrict__ WB)
{
    const int tid = threadIdx.x;
    const int l = tid & 63, w = tid >> 6, lr = l & 31, lh = l >> 5;
    const int wr = w >> 2, wc = w & 3;
    int b, r0;
    if (COMPACT) { b = blockIdx.x / CBLK; r0 = (blockIdx.x % CBLK)*SROWS; if (r0 >= cnt[b]) return; }
    else         { b = blockIdx.x / SBPB; r0 = (blockIdx.x % SBPB)*SROWS; }

    __shared__ __align__(16) f16 hb[SROWS*256];
    __shared__ int earr[SROWS];
    __shared__ unsigned char mlds[Nn];
    __shared__ int anyv;

    if (!COMPACT) { if (tid < Nn) mlds[tid] = mask[b*Nn + tid]; if (tid == 0) anyv = 0; }
    if (tid < SROWS) {
        if (COMPACT) { int r = r0 + tid; earr[tid] = (r < cnt[b]) ? vlist[b*MAXV + r] : -1; }
        else earr[tid] = r0 + tid;
    }
    __syncthreads();

    bool rv;
    {
        int e = earr[32*wr + lr];
        if (!COMPACT) {
            rv = row_valid(e, mlds);
            if (__any(rv)) anyv = 1;
            __syncthreads();
            if (!anyv) return;
        } else rv = (e >= 0);
    }

    // phase A: gather x rows -> f16 LDS cols [128,256)
    #pragma unroll
    for (int p = 0; p < 2; ++p) {
        const int row = p*32 + (tid >> 4);
        const int c0  = (tid & 15)*8;
        int e = earr[row]; if (e < 0) e = 0;
        const float4 x0 = *(const float4*)&x[((long)(b*NCUBE + e))*128 + c0];
        const float4 x1 = *(const float4*)&x[((long)(b*NCUBE + e))*128 + c0 + 4];
        f16x8 v; v[0]=(f16)x0.x; v[1]=(f16)x0.y; v[2]=(f16)x0.z; v[3]=(f16)x0.w;
                 v[4]=(f16)x1.x; v[5]=(f16)x1.y; v[6]=(f16)x1.z; v[7]=(f16)x1.w;
        *(f16x8*)&hb[swzofs(row, 128 + c0)] = v;
    }
    __syncthreads();

    // stage 1: h1 = relu(x @ Wi1 + bi1) -> cols [0,128)
    f32x16 acc;
    #pragma unroll
    for (int rg = 0; rg < 4; ++rg) {
        const float4 bv = *(const float4*)(bi1 + 32*wc + 8*rg + 4*lh);
        acc[rg*4+0]=bv.x; acc[rg*4+1]=bv.y; acc[rg*4+2]=bv.z; acc[rg*4+3]=bv.w;
    }
    #pragma unroll
    for (int kt = 0; kt < 8; ++kt) {
        const f16x8 wf = load_wfrag<PRE>(WB+OFF_WI1, Wi1, 128, 4, kt, wc, l);
        const f16x8 af = lds_af(hb, 32*wr, 16, kt, l);
        acc = __builtin_amdgcn_mfma_f32_32x32x16_f16(wf, af, acc, 0, 0, 0);
    }
    #pragma unroll
    for (int rg = 0; rg < 4; ++rg) {
        f16x4 v;
        #pragma unroll
        for (int q = 0; q < 4; ++q) v[q] = (f16)fmaxf(acc[rg*4+q], 0.f);
        *(f16x4*)&hb[swzofs(32*wr + lr, 32*wc + 8*rg + 4*lh)] = v;
    }
    __syncthreads();

    // stage 2: xf = h1 @ Wi2 + bi2
    #pragma unroll
    for (int rg = 0; rg < 4; ++rg) {
        const float4 bv = *(const float4*)(bi2 + 32*wc + 8*rg + 4*lh);
        acc[rg*4+0]=bv.x; acc[rg*4+1]=bv.y; acc[rg*4+2]=bv.z; acc[rg*4+3]=bv.w;
    }
    #pragma unroll
    for (int kt = 0; kt < 8; ++kt) {
        const f16x8 wf = load_wfrag<PRE>(WB+OFF_WI2, Wi2, 128, 4, kt, wc, l);
        const f16x8 af = lds_af(hb, 32*wr, 0, kt, l);
        acc = __builtin_amdgcn_mfma_f32_32x32x16_f16(wf, af, acc, 0, 0, 0);
    }

    // masked exp-sum of f16-rounded xf (consistent with full's recompute);
    // butterfly over 32 rows, atomics from lr==0 lanes only.
    float s[16];
    #pragma unroll
    for (int r = 0; r < 16; ++r) s[r] = rv ? __expf((float)(f16)acc[r]) : 0.0f;
    #pragma unroll
    for (int r = 0; r < 16; ++r) {
        float v = s[r];
        v += __shfl_xor(v, 1); v += __shfl_xor(v, 2);
        v += __shfl_xor(v, 4); v += __shfl_xor(v, 8); v += __shfl_xor(v, 16);
        if (lr == 0) atomicAdd(&sums[b*128 + 32*wc + 8*(r>>2) + 4*lh + (r&3)], v);
    }
}

// ---------------------------------------------------------------------------
// Full kernel: all 5 stages over 128-row tiles. 8 waves = 2 row-groups
// (wr: 64 rows, mt-pair of 32) x 4 col-slices (wc). 32x32x16 MFMA.
// Single f16 [128][256] LDS tile (swizzled):
//   phA: x -> [128,256) | s1: h1 -> [0,128) | s2: xf -> [128,256), acc2 := a
//   s3: a*xi -> [0,128) | s4: K=256 over [a*xi | xf] | s5: 256->1 reduce.
// R10 changes vs verified R6 full: W-frags hoisted in s1/s2/s3 (one latency
// exposure per stage), 2-deep W prefetch in s4 (both patterns verified in
// R8/R9's out_kernel).
// ---------------------------------------------------------------------------
template<bool PRE>
__global__ __launch_bounds__(512, 4)
void full_kernel(const float* __restrict__ x, const unsigned char* __restrict__ mask,
                 const float* __restrict__ Wi1, const float* __restrict__ bi1,
                 const float* __restrict__ Wi2, const float* __restrict__ bi2,
                 const float* __restrict__ We,
                 const float* __restrict__ Wo1, const float* __restrict__ bo1,
                 const float* __restrict__ Wo2, const float* __restrict__ bo2,
                 const float* __restrict__ sums, const f16* __restrict__ WB,
                 float* __restrict__ out)
{
    const int tid = threadIdx.x;
    const int l = tid & 63, w = tid >> 6, lr = l & 31, lh = l >> 5;
    const int wr = w >> 2, wc = w & 3;
    const int b = blockIdx.x / BPB;
    const int e0 = (blockIdx.x % BPB) * ROWS;

    __shared__ __align__(16) f16 hb[ROWS*256];   // 64 KB
    __shared__ float red[8][64];
    __shared__ unsigned char mlds[Nn];

    if (tid < Nn) mlds[tid] = mask[b*Nn + tid];

    // phA: x tile -> f16 LDS cols [128,256)
    #pragma unroll
    for (int p = 0; p < 4; ++p) {
        const int row = p*32 + (tid >> 4);
        const int c0  = (tid & 15)*8;
        const long base = ((long)(b*NCUBE + e0 + row))*128 + c0;
        const float4 x0 = *(const float4*)&x[base];
        const float4 x1 = *(const float4*)&x[base + 4];
        f16x8 v; v[0]=(f16)x0.x; v[1]=(f16)x0.y; v[2]=(f16)x0.z; v[3]=(f16)x0.w;
                 v[4]=(f16)x1.x; v[5]=(f16)x1.y; v[6]=(f16)x1.z; v[7]=(f16)x1.w;
        *(f16x8*)&hb[swzofs(row, 128 + c0)] = v;
    }
    __syncthreads();

    bool valid[2];
    #pragma unroll
    for (int mt = 0; mt < 2; ++mt)
        valid[mt] = row_valid(e0 + 64*wr + 32*mt + lr, mlds);

    // ---- stage 1: h1 = relu(x @ Wi1 + bi1) -> cols [0,128). W hoisted. ----
    {
        f16x8 wfr[8];
        #pragma unroll
        for (int kt = 0; kt < 8; ++kt)
            wfr[kt] = load_wfrag<PRE>(WB+OFF_WI1, Wi1, 128, 4, kt, wc, l);
        f32x16 acc1[2];
        #pragma unroll
        for (int rg = 0; rg < 4; ++rg) {
            const float4 bv = *(const float4*)(bi1 + 32*wc + 8*rg + 4*lh);
            #pragma unroll
            for (int mt = 0; mt < 2; ++mt) {
                acc1[mt][rg*4+0]=bv.x; acc1[mt][rg*4+1]=bv.y;
                acc1[mt][rg*4+2]=bv.z; acc1[mt][rg*4+3]=bv.w;
            }
        }
        #pragma unroll
        for (int kt = 0; kt < 8; ++kt)
            #pragma unroll
            for (int mt = 0; mt < 2; ++mt) {
                const f16x8 af = lds_af(hb, 64*wr + 32*mt, 16, kt, l);
                acc1[mt] = __builtin_amdgcn_mfma_f32_32x32x16_f16(wfr[kt], af, acc1[mt], 0, 0, 0);
            }
        #pragma unroll
        for (int mt = 0; mt < 2; ++mt)
            #pragma unroll
            for (int rg = 0; rg < 4; ++rg) {
                f16x4 v;
                #pragma unroll
                for (int q = 0; q < 4; ++q) v[q] = (f16)fmaxf(acc1[mt][rg*4+q], 0.f);
                *(f16x4*)&hb[swzofs(64*wr + 32*mt + lr, 32*wc + 8*rg + 4*lh)] = v;
            }
    }
    __syncthreads();

    // ---- stage 2: xf = h1 @ Wi2 + bi2 -> [128,256); acc2 := a. W hoisted. ----
    f32x16 acc2[2];
    {
        f16x8 wfr[8];
        #pragma unroll
        for (int kt = 0; kt < 8; ++kt)
            wfr[kt] = load_wfrag<PRE>(WB+OFF_WI2, Wi2, 128, 4, kt, wc, l);
        #pragma unroll
        for (int rg = 0; rg < 4; ++rg) {
            const float4 bv = *(const float4*)(bi2 + 32*wc + 8*rg + 4*lh);
            #pragma unroll
            for (int mt = 0; mt < 2; ++mt) {
                acc2[mt][rg*4+0]=bv.x; acc2[mt][rg*4+1]=bv.y;
                acc2[mt][rg*4+2]=bv.z; acc2[mt][rg*4+3]=bv.w;
            }
        }
        #pragma unroll
        for (int kt = 0; kt < 8; ++kt)
            #pragma unroll
            for (int mt = 0; mt < 2; ++mt) {
                const f16x8 af = lds_af(hb, 64*wr + 32*mt, 0, kt, l);
                acc2[mt] = __builtin_amdgcn_mfma_f32_32x32x16_f16(wfr[kt], af, acc2[mt], 0, 0, 0);
            }
        // x region dead after s1's barrier: write f16 xf there; exp uses the
        // SAME f16-rounded values (consistent with sums_kernel).
        #pragma unroll
        for (int mt = 0; mt < 2; ++mt)
            #pragma unroll
            for (int rg = 0; rg < 4; ++rg) {
                f16x4 v;
                #pragma unroll
                for (int q = 0; q < 4; ++q) v[q] = (f16)acc2[mt][rg*4+q];
                *(f16x4*)&hb[swzofs(64*wr + 32*mt + lr, 128 + 32*wc + 8*rg + 4*lh)] = v;
                #pragma unroll
                for (int q = 0; q < 4; ++q) acc2[mt][rg*4+q] = (float)v[q];
            }
        #pragma unroll
        for (int rg = 0; rg < 4; ++rg) {
            const float4 sv = *(const float4*)(sums + b*128 + 32*wc + 8*rg + 4*lh);
            const float rinv[4] = {1.f/sv.x, 1.f/sv.y, 1.f/sv.z, 1.f/sv.w};
            #pragma unroll
            for (int mt = 0; mt < 2; ++mt)
                #pragma unroll
                for (int q = 0; q < 4; ++q)
                    acc2[mt][rg*4+q] = valid[mt] ? __expf(acc2[mt][rg*4+q]) * rinv[q] : 0.0f;
        }
    }
    __syncthreads();

    // ---- stage 3: xi = relu(xf @ We); a*xi -> cols [0,128). W hoisted. ----
    {
        f16x8 wfr[8];
        #pragma unroll
        for (int kt = 0; kt < 8; ++kt)
            wfr[kt] = load_wfrag<PRE>(WB+OFF_WE, We, 128, 4, kt, wc, l);
        f32x16 acc3[2];
        #pragma unroll
        for (int mt = 0; mt < 2; ++mt)
            #pragma unroll
            for (int r = 0; r < 16; ++r) acc3[mt][r] = 0.f;
        #pragma unroll
        for (int kt = 0; kt < 8; ++kt)
            #pragma unroll
            for (int mt = 0; mt < 2; ++mt) {
                const f16x8 af = lds_af(hb, 64*wr + 32*mt, 16, kt, l);
                acc3[mt] = __builtin_amdgcn_mfma_f32_32x32x16_f16(wfr[kt], af, acc3[mt], 0, 0, 0);
            }
        #pragma unroll
        for (int mt = 0; mt < 2; ++mt)
            #pragma unroll
            for (int rg = 0; rg < 4; ++rg) {
                f16x4 v;
                #pragma unroll
                for (int q = 0; q < 4; ++q)
                    v[q] = (f16)(acc2[mt][rg*4+q] * fmaxf(acc3[mt][rg*4+q], 0.f));
                *(f16x4*)&hb[swzofs(64*wr + 32*mt + lr, 32*wc + 8*rg + 4*lh)] = v;
            }
    }
    __syncthreads();

    // ---- stage 4: g = relu(h @ Wo1 + bo1), K=256, 2-deep W prefetch ----
    f32x16 acc4[2][2];
    #pragma unroll
    for (int ntl = 0; ntl < 2; ++ntl)
        #pragma unroll
        for (int rg = 0; rg < 4; ++rg) {
            const float4 bv = *(const float4*)(bo1 + 64*wc + 32*ntl + 8*rg + 4*lh);
            #pragma unroll
            for (int mt = 0; mt < 2; ++mt) {
                acc4[mt][ntl][rg*4+0]=bv.x; acc4[mt][ntl][rg*4+1]=bv.y;
                acc4[mt][ntl][rg*4+2]=bv.z; acc4[mt][ntl][rg*4+3]=bv.w;
            }
        }
    {
        f16x8 of0 = load_wfrag<PRE>(WB+OFF_WO1, Wo1, 256, 8, 0, 2*wc+0, l);
        f16x8 of1 = load_wfrag<PRE>(WB+OFF_WO1, Wo1, 256, 8, 0, 2*wc+1, l);
        #pragma unroll
        for (int kt = 0; kt < 16; ++kt) {
            f16x8 nf0 = of0, nf1 = of1;
            if (kt < 15) {
                nf0 = load_wfrag<PRE>(WB+OFF_WO1, Wo1, 256, 8, kt+1, 2*wc+0, l);
                nf1 = load_wfrag<PRE>(WB+OFF_WO1, Wo1, 256, 8, kt+1, 2*wc+1, l);
            }
            #pragma unroll
            for (int mt = 0; mt < 2; ++mt) {
                const f16x8 af = lds_af(hb, 64*wr + 32*mt, 0, kt, l);
                acc4[mt][0] = __builtin_amdgcn_mfma_f32_32x32x16_f16(of0, af, acc4[mt][0], 0, 0, 0);
                acc4[mt][1] = __builtin_amdgcn_mfma_f32_32x32x16_f16(of1, af, acc4[mt][1], 0, 0, 0);
            }
            of0 = nf0; of1 = nf1;
        }
    }

    // ---- stage 5: out = relu(g) @ Wo2 + bo2, reduce 256 -> 1 per row ----
    {
        float outp[2] = {0.f, 0.f};
        #pragma unroll
        for (int ntl = 0; ntl < 2; ++ntl)
            #pragma unroll
            for (int rg = 0; rg < 4; ++rg) {
                const float4 wv = *(const float4*)(Wo2 + 64*wc + 32*ntl + 8*rg + 4*lh);
                #pragma unroll
                for (int mt = 0; mt < 2; ++mt) {
                    outp[mt] += fmaxf(acc4[mt][ntl][rg*4+0], 0.f)*wv.x
                              + fmaxf(acc4[mt][ntl][rg*4+1], 0.f)*wv.y
                              + fmaxf(acc4[mt][ntl][rg*4+2], 0.f)*wv.z
                              + fmaxf(acc4[mt][ntl][rg*4+3], 0.f)*wv.w;
                }
            }
        #pragma unroll
        for (int mt = 0; mt < 2; ++mt) outp[mt] += __shfl_xor(outp[mt], 32);
        if (l < 32) {
            red[w][lr]      = outp[0];
            red[w][32 + lr] = outp[1];
        }
        __syncthreads();
        if (tid < ROWS) {
            const int wr2 = tid >> 6, idx = tid & 63;
            out[(long)b*NCUBE + e0 + tid] =
                red[wr2*4+0][idx] + red[wr2*4+1][idx] +
                red[wr2*4+2][idx] + red[wr2*4+3][idx] + bo2[0];
        }
    }
}

extern "C" void kernel_launch(void* const* d_in, const int* in_sizes, int n_in,
                              void* d_out, int out_size, void* d_ws, size_t ws_size,
                              hipStream_t stream) {
    const float*         x    = (const float*)d_in[0];
    const unsigned char* mask = (const unsigned char*)d_in[1];
    const float* Wi1 = (const float*)d_in[2];
    const float* bi1 = (const float*)d_in[3];
    const float* Wi2 = (const float*)d_in[4];
    const float* bi2 = (const float*)d_in[5];
    const float* We  = (const float*)d_in[6];
    const float* Wo1 = (const float*)d_in[7];
    const float* bo1 = (const float*)d_in[8];
    const float* Wo2 = (const float*)d_in[9];
    const float* bo2 = (const float*)d_in[10];
    float* out  = (float*)d_out;
    float* sums = (float*)d_ws;
    int*   cnt   = (int*)((char*)d_ws + 2048);
    int*   vlist = (int*)((char*)d_ws + 4096);

    const bool compact = ws_size >= (size_t)(WBOFF_COMPACT + WB_BYTES);
    const size_t wboff = compact ? WBOFF_COMPACT : WBOFF_SMALL;
    const bool pre     = ws_size >= wboff + WB_BYTES;
    f16* WB = (f16*)((char*)d_ws + wboff);

    hipMemsetAsync(d_ws, 0, 2048 + Bn*sizeof(int), stream);

    if (compact) {
        prepcount_kernel<<<1056, 256, 0, stream>>>(Wi1, Wi2, We, Wo1, WB, mask, cnt, vlist);
        sums_kernel<true, true><<<Bn*CBLK, 512, 0, stream>>>(x, mask, Wi1, bi1, Wi2, bi2,
                                                             sums, cnt, vlist, WB);
        full_kernel<true><<<Bn*BPB, 512, 0, stream>>>(x, mask, Wi1, bi1, Wi2, bi2, We,
                                                      Wo1, bo1, Wo2, bo2, sums, WB, out);
    } else if (pre) {
        prepcount_kernel<<<56, 256, 0, stream>>>(Wi1, Wi2, We, Wo1, WB, mask, cnt, vlist);
        sums_kernel<true, false><<<Bn*SBPB, 512, 0, stream>>>(x, mask, Wi1, bi1, Wi2, bi2,
                                                              sums, cnt, vlist, WB);
        full_kernel<true><<<Bn*BPB, 512, 0, stream>>>(x, mask, Wi1, bi1, Wi2, bi2, We,
                                                      Wo1, bo1, Wo2, bo2, sums, WB, out);
    } else {
        sums_kernel<false, false><<<Bn*SBPB, 512, 0, stream>>>(x, mask, Wi1, bi1, Wi2, bi2,
                                                               sums, cnt, vlist, WB);
        full_kernel<false><<<Bn*BPB, 512, 0, stream>>>(x, mask, Wi1, bi1, Wi2, bi2, We,
                                                       Wo1, bo1, Wo2, bo2, sums, WB, out);
    }
}

// Round 11
// 252.595 us; speedup vs baseline: 4.0410x; 1.0358x over previous
//
#include <hip/hip_runtime.h>

#define Bn 4
#define Nn 40
#define NCUBE 64000   // 40^3
#define ROWS 64       // rows per full tile (R11: halved -> 4 blocks/CU)
#define BPB  1000     // full blocks per batch
#define SROWS 64      // rows per sums tile
#define SBPB 1000     // dense-sums blocks per batch
#define MAXV 16384    // valid-row list capacity (>= C(40,3)=9880)
#define CBLK 160      // compact-sums blocks per batch

typedef _Float16 f16;
typedef __attribute__((ext_vector_type(8)))  _Float16 f16x8;
typedef __attribute__((ext_vector_type(4)))  _Float16 f16x4;
typedef __attribute__((ext_vector_type(16))) float    f32x16;

// ---------------- workspace layout (bytes) ----------------
// 0      : sums[Bn*128] f32
// 2048   : cnt[Bn] int
// 4096   : vlist[Bn*MAXV] int        (compact tier only)
// WBOFF  : f16 weight A-fragments (offsets below in halfs)
#define OFF_WI1 0
#define OFF_WI2 16384
#define OFF_WE  32768
#define OFF_WO1 49152
#define WB_HALFS 114688
#define WB_BYTES (WB_HALFS*2)
#define WBOFF_COMPACT (4096 + Bn*MAXV*4)   // 266240
#define WBOFF_SMALL   2560

// 16B-granule XOR swizzle for [rows][256]-f16 LDS tiles (f16 units).
__device__ __forceinline__ int swz8(int row, int colg) {
    return row*256 + (((colg & ~7) | ((colg ^ row) & 7)) << 3);
}
__device__ __forceinline__ int swzofs(int row, int col) {
    return swz8(row, col >> 3) + (col & 7);
}

// Weight A-fragment for mfma_f32_32x32x16_f16 with SWAPPED operands
// (arg0 = W-frag): lane l, j holds W[kt*16 + 8*(l>>5) + j][nt*32 + (l&31)].
// D maps: chan = nt*32 + (reg&3)+8*(reg>>2)+4*(l>>5), act_row = base + (l&31).
template<bool PRE>
__device__ __forceinline__ f16x8 load_wfrag(const f16* __restrict__ WF,
                                            const float* __restrict__ W,
                                            int N, int NT, int kt, int nt, int l) {
    if constexpr (PRE) {
        return *(const f16x8*)(WF + ((kt*NT + nt)*64 + l)*8);
    } else {
        const int col = nt*32 + (l & 31);
        const int k0  = kt*16 + 8*(l >> 5);
        f16x8 r;
        #pragma unroll
        for (int j = 0; j < 8; ++j) r[j] = (f16)W[(k0 + j)*N + col];
        return r;
    }
}

// Activation B-fragment via swizzled ds_read_b128.
__device__ __forceinline__ f16x8 lds_af(const f16* hb, int rowbase, int areag, int kt, int l) {
    return *(const f16x8*)&hb[swz8(rowbase + (l & 31), areag + 2*kt + (l >> 5))];
}

__device__ __forceinline__ bool row_valid(int e, const unsigned char* mlds) {
    int k = e % Nn, ij = e / Nn, j = ij % Nn, i = ij / Nn;
    return (i < j) && (j < k) && mlds[i] && mlds[j] && mlds[k];
}

// ---------------------------------------------------------------------------
// One-time weight conversion into A-fragment layout + valid-row compaction.
// Blocks [0,56): prep.  Blocks [56,1056): ballot compaction.
// ---------------------------------------------------------------------------
__global__ __launch_bounds__(256)
void prepcount_kernel(const float* __restrict__ Wi1, const float* __restrict__ Wi2,
                      const float* __restrict__ We,  const float* __restrict__ Wo1,
                      f16* __restrict__ WB, const unsigned char* __restrict__ mask,
                      int* __restrict__ cnt, int* __restrict__ vlist) {
    const int blk = blockIdx.x;
    if (blk < 56) {
        int id = blk*256 + threadIdx.x;   // 0..14335
        const float* W; int NT, N; f16* WF; int fid;
        if (id < 2048)      { W = Wi1; NT = 4; N = 128; WF = WB+OFF_WI1; fid = id; }
        else if (id < 4096) { W = Wi2; NT = 4; N = 128; WF = WB+OFF_WI2; fid = id-2048; }
        else if (id < 6144) { W = We;  NT = 4; N = 128; WF = WB+OFF_WE;  fid = id-4096; }
        else                { W = Wo1; NT = 8; N = 256; WF = WB+OFF_WO1; fid = id-6144; }
        int frag = fid >> 6, l = fid & 63;
        int nt = frag % NT, kt = frag / NT;
        int col = nt*32 + (l & 31), k0 = kt*16 + 8*(l >> 5);
        #pragma unroll
        for (int j = 0; j < 8; ++j) WF[frag*512 + l*8 + j] = (f16)W[(k0 + j)*N + col];
    } else {
        const int idx = (blk - 56)*256 + threadIdx.x;   // 0..255999
        const int b = idx / NCUBE, e = idx % NCUBE;
        const int k = e % Nn, ij = e / Nn, j = ij % Nn, i = ij / Nn;
        const bool v = (i < j) && (j < k) &&
                       mask[b*Nn+i] && mask[b*Nn+j] && mask[b*Nn+k];
        const unsigned long long m = __ballot(v);
        const int lane = threadIdx.x & 63;
        const int c = __popcll(m);
        int base = 0;
        if (lane == 0 && c) base = atomicAdd(&cnt[b], c);
        base = __shfl(base, 0);
        if (v) vlist[b*MAXV + base + __popcll(m & ((1ull<<lane)-1ull))] = e;
    }
}

// ---------------------------------------------------------------------------
// Sums kernel: stages 1-2 + masked exp-sum over 64-row tiles. 8 waves =
// 2 row-groups (wr) x 4 col-slices (wc). 32x32x16 MFMA. (Verified R6/R10.)
// ---------------------------------------------------------------------------
template<bool PRE, bool COMPACT>
__global__ __launch_bounds__(512, 4)
void sums_kernel(const float* __restrict__ x, const unsigned char* __restrict__ mask,
                 const float* __restrict__ Wi1, const float* __restrict__ bi1,
                 const float* __restrict__ Wi2, const float* __restrict__ bi2,
                 float* __restrict__ sums, const int* __restrict__ cnt,
                 const int* __restrict__ vlist, const f16* __restrict__ WB)
{
    const int tid = threadIdx.x;
    const int l = tid & 63, w = tid >> 6, lr = l & 31, lh = l >> 5;
    const int wr = w >> 2, wc = w & 3;
    int b, r0;
    if (COMPACT) { b = blockIdx.x / CBLK; r0 = (blockIdx.x % CBLK)*SROWS; if (r0 >= cnt[b]) return; }
    else         { b = blockIdx.x / SBPB; r0 = (blockIdx.x % SBPB)*SROWS; }

    __shared__ __align__(16) f16 hb[SROWS*256];
    __shared__ int earr[SROWS];
    __shared__ unsigned char mlds[Nn];
    __shared__ int anyv;

    if (!COMPACT) { if (tid < Nn) mlds[tid] = mask[b*Nn + tid]; if (tid == 0) anyv = 0; }
    if (tid < SROWS) {
        if (COMPACT) { int r = r0 + tid; earr[tid] = (r < cnt[b]) ? vlist[b*MAXV + r] : -1; }
        else earr[tid] = r0 + tid;
    }
    __syncthreads();

    bool rv;
    {
        int e = earr[32*wr + lr];
        if (!COMPACT) {
            rv = row_valid(e, mlds);
            if (__any(rv)) anyv = 1;
            __syncthreads();
            if (!anyv) return;
        } else rv = (e >= 0);
    }

    #pragma unroll
    for (int p = 0; p < 2; ++p) {
        const int row = p*32 + (tid >> 4);
        const int c0  = (tid & 15)*8;
        int e = earr[row]; if (e < 0) e = 0;
        const float4 x0 = *(const float4*)&x[((long)(b*NCUBE + e))*128 + c0];
        const float4 x1 = *(const float4*)&x[((long)(b*NCUBE + e))*128 + c0 + 4];
        f16x8 v; v[0]=(f16)x0.x; v[1]=(f16)x0.y; v[2]=(f16)x0.z; v[3]=(f16)x0.w;
                 v[4]=(f16)x1.x; v[5]=(f16)x1.y; v[6]=(f16)x1.z; v[7]=(f16)x1.w;
        *(f16x8*)&hb[swzofs(row, 128 + c0)] = v;
    }
    __syncthreads();

    f32x16 acc;
    #pragma unroll
    for (int rg = 0; rg < 4; ++rg) {
        const float4 bv = *(const float4*)(bi1 + 32*wc + 8*rg + 4*lh);
        acc[rg*4+0]=bv.x; acc[rg*4+1]=bv.y; acc[rg*4+2]=bv.z; acc[rg*4+3]=bv.w;
    }
    #pragma unroll
    for (int kt = 0; kt < 8; ++kt) {
        const f16x8 wf = load_wfrag<PRE>(WB+OFF_WI1, Wi1, 128, 4, kt, wc, l);
        const f16x8 af = lds_af(hb, 32*wr, 16, kt, l);
        acc = __builtin_amdgcn_mfma_f32_32x32x16_f16(wf, af, acc, 0, 0, 0);
    }
    #pragma unroll
    for (int rg = 0; rg < 4; ++rg) {
        f16x4 v;
        #pragma unroll
        for (int q = 0; q < 4; ++q) v[q] = (f16)fmaxf(acc[rg*4+q], 0.f);
        *(f16x4*)&hb[swzofs(32*wr + lr, 32*wc + 8*rg + 4*lh)] = v;
    }
    __syncthreads();

    #pragma unroll
    for (int rg = 0; rg < 4; ++rg) {
        const float4 bv = *(const float4*)(bi2 + 32*wc + 8*rg + 4*lh);
        acc[rg*4+0]=bv.x; acc[rg*4+1]=bv.y; acc[rg*4+2]=bv.z; acc[rg*4+3]=bv.w;
    }
    #pragma unroll
    for (int kt = 0; kt < 8; ++kt) {
        const f16x8 wf = load_wfrag<PRE>(WB+OFF_WI2, Wi2, 128, 4, kt, wc, l);
        const f16x8 af = lds_af(hb, 32*wr, 0, kt, l);
        acc = __builtin_amdgcn_mfma_f32_32x32x16_f16(wf, af, acc, 0, 0, 0);
    }

    float s[16];
    #pragma unroll
    for (int r = 0; r < 16; ++r) s[r] = rv ? __expf((float)(f16)acc[r]) : 0.0f;
    #pragma unroll
    for (int r = 0; r < 16; ++r) {
        float v = s[r];
        v += __shfl_xor(v, 1); v += __shfl_xor(v, 2);
        v += __shfl_xor(v, 4); v += __shfl_xor(v, 8); v += __shfl_xor(v, 16);
        if (lr == 0) atomicAdd(&sums[b*128 + 32*wc + 8*(r>>2) + 4*lh + (r&3)], v);
    }
}

// ---------------------------------------------------------------------------
// Full kernel (R11): 64-row tiles, 256 threads = 4 waves. Wave w owns cols
// [32w,32w+32) in s1-3 (mt=2 row-halves) and cols [64w,64w+64) in s4
// (ntl=0,1). LDS 33 KB -> 4 blocks/CU: 2x the independent blocks per CU for
// barrier-drain overlap (the one lever the 106us plateau hasn't tested).
// W hoisted in s1/s2/s3; s4 2-deep W prefetch. Math identical to R10.
// ---------------------------------------------------------------------------
template<bool PRE>
__global__ __launch_bounds__(256, 4)
void full_kernel(const float* __restrict__ x, const unsigned char* __restrict__ mask,
                 const float* __restrict__ Wi1, const float* __restrict__ bi1,
                 const float* __restrict__ Wi2, const float* __restrict__ bi2,
                 const float* __restrict__ We,
                 const float* __restrict__ Wo1, const float* __restrict__ bo1,
                 const float* __restrict__ Wo2, const float* __restrict__ bo2,
                 const float* __restrict__ sums, const f16* __restrict__ WB,
                 float* __restrict__ out)
{
    const int tid = threadIdx.x;
    const int l = tid & 63, w = tid >> 6, lr = l & 31, lh = l >> 5;
    const int b = blockIdx.x / BPB;
    const int e0 = (blockIdx.x % BPB) * ROWS;

    __shared__ __align__(16) f16 hb[ROWS*256];   // 32 KB
    __shared__ float red[4][ROWS];
    __shared__ unsigned char mlds[Nn];

    if (tid < Nn) mlds[tid] = mask[b*Nn + tid];

    // phA: x tile -> f16 LDS cols [128,256)
    #pragma unroll
    for (int p = 0; p < 4; ++p) {
        const int row = p*16 + (tid >> 4);
        const int c0  = (tid & 15)*8;
        const long base = ((long)(b*NCUBE + e0 + row))*128 + c0;
        const float4 x0 = *(const float4*)&x[base];
        const float4 x1 = *(const float4*)&x[base + 4];
        f16x8 v; v[0]=(f16)x0.x; v[1]=(f16)x0.y; v[2]=(f16)x0.z; v[3]=(f16)x0.w;
                 v[4]=(f16)x1.x; v[5]=(f16)x1.y; v[6]=(f16)x1.z; v[7]=(f16)x1.w;
        *(f16x8*)&hb[swzofs(row, 128 + c0)] = v;
    }
    __syncthreads();

    bool valid[2];
    #pragma unroll
    for (int mt = 0; mt < 2; ++mt)
        valid[mt] = row_valid(e0 + 32*mt + lr, mlds);

    // ---- stage 1: h1 = relu(x @ Wi1 + bi1) -> cols [0,128). W hoisted. ----
    {
        f16x8 wfr[8];
        #pragma unroll
        for (int kt = 0; kt < 8; ++kt)
            wfr[kt] = load_wfrag<PRE>(WB+OFF_WI1, Wi1, 128, 4, kt, w, l);
        f32x16 acc1[2];
        #pragma unroll
        for (int rg = 0; rg < 4; ++rg) {
            const float4 bv = *(const float4*)(bi1 + 32*w + 8*rg + 4*lh);
            #pragma unroll
            for (int mt = 0; mt < 2; ++mt) {
                acc1[mt][rg*4+0]=bv.x; acc1[mt][rg*4+1]=bv.y;
                acc1[mt][rg*4+2]=bv.z; acc1[mt][rg*4+3]=bv.w;
            }
        }
        #pragma unroll
        for (int kt = 0; kt < 8; ++kt)
            #pragma unroll
            for (int mt = 0; mt < 2; ++mt) {
                const f16x8 af = lds_af(hb, 32*mt, 16, kt, l);
                acc1[mt] = __builtin_amdgcn_mfma_f32_32x32x16_f16(wfr[kt], af, acc1[mt], 0, 0, 0);
            }
        #pragma unroll
        for (int mt = 0; mt < 2; ++mt)
            #pragma unroll
            for (int rg = 0; rg < 4; ++rg) {
                f16x4 v;
                #pragma unroll
                for (int q = 0; q < 4; ++q) v[q] = (f16)fmaxf(acc1[mt][rg*4+q], 0.f);
                *(f16x4*)&hb[swzofs(32*mt + lr, 32*w + 8*rg + 4*lh)] = v;
            }
    }
    __syncthreads();

    // ---- stage 2: xf = h1 @ Wi2 + bi2 -> [128,256); acc2 := a. W hoisted. ----
    f32x16 acc2[2];
    {
        f16x8 wfr[8];
        #pragma unroll
        for (int kt = 0; kt < 8; ++kt)
            wfr[kt] = load_wfrag<PRE>(WB+OFF_WI2, Wi2, 128, 4, kt, w, l);
        #pragma unroll
        for (int rg = 0; rg < 4; ++rg) {
            const float4 bv = *(const float4*)(bi2 + 32*w + 8*rg + 4*lh);
            #pragma unroll
            for (int mt = 0; mt < 2; ++mt) {
                acc2[mt][rg*4+0]=bv.x; acc2[mt][rg*4+1]=bv.y;
                acc2[mt][rg*4+2]=bv.z; acc2[mt][rg*4+3]=bv.w;
            }
        }
        #pragma unroll
        for (int kt = 0; kt < 8; ++kt)
            #pragma unroll
            for (int mt = 0; mt < 2; ++mt) {
                const f16x8 af = lds_af(hb, 32*mt, 0, kt, l);
                acc2[mt] = __builtin_amdgcn_mfma_f32_32x32x16_f16(wfr[kt], af, acc2[mt], 0, 0, 0);
            }
        // x region dead after s1's barrier: write f16 xf there; exp uses the
        // SAME f16-rounded values (consistent with sums_kernel).
        #pragma unroll
        for (int mt = 0; mt < 2; ++mt)
            #pragma unroll
            for (int rg = 0; rg < 4; ++rg) {
                f16x4 v;
                #pragma unroll
                for (int q = 0; q < 4; ++q) v[q] = (f16)acc2[mt][rg*4+q];
                *(f16x4*)&hb[swzofs(32*mt + lr, 128 + 32*w + 8*rg + 4*lh)] = v;
                #pragma unroll
                for (int q = 0; q < 4; ++q) acc2[mt][rg*4+q] = (float)v[q];
            }
        #pragma unroll
        for (int rg = 0; rg < 4; ++rg) {
            const float4 sv = *(const float4*)(sums + b*128 + 32*w + 8*rg + 4*lh);
            const float rinv[4] = {1.f/sv.x, 1.f/sv.y, 1.f/sv.z, 1.f/sv.w};
            #pragma unroll
            for (int mt = 0; mt < 2; ++mt)
                #pragma unroll
                for (int q = 0; q < 4; ++q)
                    acc2[mt][rg*4+q] = valid[mt] ? __expf(acc2[mt][rg*4+q]) * rinv[q] : 0.0f;
        }
    }
    __syncthreads();

    // ---- stage 3: xi = relu(xf @ We); a*xi -> cols [0,128). W hoisted. ----
    {
        f16x8 wfr[8];
        #pragma unroll
        for (int kt = 0; kt < 8; ++kt)
            wfr[kt] = load_wfrag<PRE>(WB+OFF_WE, We, 128, 4, kt, w, l);
        f32x16 acc3[2];
        #pragma unroll
        for (int mt = 0; mt < 2; ++mt)
            #pragma unroll
            for (int r = 0; r < 16; ++r) acc3[mt][r] = 0.f;
        #pragma unroll
        for (int kt = 0; kt < 8; ++kt)
            #pragma unroll
            for (int mt = 0; mt < 2; ++mt) {
                const f16x8 af = lds_af(hb, 32*mt, 16, kt, l);
                acc3[mt] = __builtin_amdgcn_mfma_f32_32x32x16_f16(wfr[kt], af, acc3[mt], 0, 0, 0);
            }
        #pragma unroll
        for (int mt = 0; mt < 2; ++mt)
            #pragma unroll
            for (int rg = 0; rg < 4; ++rg) {
                f16x4 v;
                #pragma unroll
                for (int q = 0; q < 4; ++q)
                    v[q] = (f16)(acc2[mt][rg*4+q] * fmaxf(acc3[mt][rg*4+q], 0.f));
                *(f16x4*)&hb[swzofs(32*mt + lr, 32*w + 8*rg + 4*lh)] = v;
            }
    }
    __syncthreads();

    // ---- stage 4: g = relu(h @ Wo1 + bo1), K=256, 2-deep W prefetch.
    //      wave w owns chans [64w, 64w+64) = nt 2w, 2w+1; mt=2 row-halves. ----
    f32x16 acc4[2][2];
    #pragma unroll
    for (int ntl = 0; ntl < 2; ++ntl)
        #pragma unroll
        for (int rg = 0; rg < 4; ++rg) {
            const float4 bv = *(const float4*)(bo1 + 64*w + 32*ntl + 8*rg + 4*lh);
            #pragma unroll
            for (int mt = 0; mt < 2; ++mt) {
                acc4[mt][ntl][rg*4+0]=bv.x; acc4[mt][ntl][rg*4+1]=bv.y;
                acc4[mt][ntl][rg*4+2]=bv.z; acc4[mt][ntl][rg*4+3]=bv.w;
            }
        }
    {
        f16x8 of0 = load_wfrag<PRE>(WB+OFF_WO1, Wo1, 256, 8, 0, 2*w+0, l);
        f16x8 of1 = load_wfrag<PRE>(WB+OFF_WO1, Wo1, 256, 8, 0, 2*w+1, l);
        #pragma unroll
        for (int kt = 0; kt < 16; ++kt) {
            f16x8 nf0 = of0, nf1 = of1;
            if (kt < 15) {
                nf0 = load_wfrag<PRE>(WB+OFF_WO1, Wo1, 256, 8, kt+1, 2*w+0, l);
                nf1 = load_wfrag<PRE>(WB+OFF_WO1, Wo1, 256, 8, kt+1, 2*w+1, l);
            }
            #pragma unroll
            for (int mt = 0; mt < 2; ++mt) {
                const f16x8 af = lds_af(hb, 32*mt, 0, kt, l);
                acc4[mt][0] = __builtin_amdgcn_mfma_f32_32x32x16_f16(of0, af, acc4[mt][0], 0, 0, 0);
                acc4[mt][1] = __builtin_amdgcn_mfma_f32_32x32x16_f16(of1, af, acc4[mt][1], 0, 0, 0);
            }
            of0 = nf0; of1 = nf1;
        }
    }

    // ---- stage 5: out = relu(g) @ Wo2 + bo2, reduce 256 -> 1 per row ----
    {
        float outp[2] = {0.f, 0.f};
        #pragma unroll
        for (int ntl = 0; ntl < 2; ++ntl)
            #pragma unroll
            for (int rg = 0; rg < 4; ++rg) {
                const float4 wv = *(const float4*)(Wo2 + 64*w + 32*ntl + 8*rg + 4*lh);
                #pragma unroll
                for (int mt = 0; mt < 2; ++mt) {
                    outp[mt] += fmaxf(acc4[mt][ntl][rg*4+0], 0.f)*wv.x
                              + fmaxf(acc4[mt][ntl][rg*4+1], 0.f)*wv.y
                              + fmaxf(acc4[mt][ntl][rg*4+2], 0.f)*wv.z
                              + fmaxf(acc4[mt][ntl][rg*4+3], 0.f)*wv.w;
                }
            }
        #pragma unroll
        for (int mt = 0; mt < 2; ++mt) outp[mt] += __shfl_xor(outp[mt], 32);
        if (l < 32) {
            red[w][lr]      = outp[0];
            red[w][32 + lr] = outp[1];
        }
        __syncthreads();
        if (tid < ROWS) {
            out[(long)b*NCUBE + e0 + tid] =
                red[0][tid] + red[1][tid] + red[2][tid] + red[3][tid] + bo2[0];
        }
    }
}

extern "C" void kernel_launch(void* const* d_in, const int* in_sizes, int n_in,
                              void* d_out, int out_size, void* d_ws, size_t ws_size,
                              hipStream_t stream) {
    const float*         x    = (const float*)d_in[0];
    const unsigned char* mask = (const unsigned char*)d_in[1];
    const float* Wi1 = (const float*)d_in[2];
    const float* bi1 = (const float*)d_in[3];
    const float* Wi2 = (const float*)d_in[4];
    const float* bi2 = (const float*)d_in[5];
    const float* We  = (const float*)d_in[6];
    const float* Wo1 = (const float*)d_in[7];
    const float* bo1 = (const float*)d_in[8];
    const float* Wo2 = (const float*)d_in[9];
    const float* bo2 = (const float*)d_in[10];
    float* out  = (float*)d_out;
    float* sums = (float*)d_ws;
    int*   cnt   = (int*)((char*)d_ws + 2048);
    int*   vlist = (int*)((char*)d_ws + 4096);

    const bool compact = ws_size >= (size_t)(WBOFF_COMPACT + WB_BYTES);
    const size_t wboff = compact ? WBOFF_COMPACT : WBOFF_SMALL;
    const bool pre     = ws_size >= wboff + WB_BYTES;
    f16* WB = (f16*)((char*)d_ws + wboff);

    hipMemsetAsync(d_ws, 0, 2048 + Bn*sizeof(int), stream);

    if (compact) {
        prepcount_kernel<<<1056, 256, 0, stream>>>(Wi1, Wi2, We, Wo1, WB, mask, cnt, vlist);
        sums_kernel<true, true><<<Bn*CBLK, 512, 0, stream>>>(x, mask, Wi1, bi1, Wi2, bi2,
                                                             sums, cnt, vlist, WB);
        full_kernel<true><<<Bn*BPB, 256, 0, stream>>>(x, mask, Wi1, bi1, Wi2, bi2, We,
                                                      Wo1, bo1, Wo2, bo2, sums, WB, out);
    } else if (pre) {
        prepcount_kernel<<<56, 256, 0, stream>>>(Wi1, Wi2, We, Wo1, WB, mask, cnt, vlist);
        sums_kernel<true, false><<<Bn*SBPB, 512, 0, stream>>>(x, mask, Wi1, bi1, Wi2, bi2,
                                                              sums, cnt, vlist, WB);
        full_kernel<true><<<Bn*BPB, 256, 0, stream>>>(x, mask, Wi1, bi1, Wi2, bi2, We,
                                                      Wo1, bo1, Wo2, bo2, sums, WB, out);
    } else {
        sums_kernel<false, false><<<Bn*SBPB, 512, 0, stream>>>(x, mask, Wi1, bi1, Wi2, bi2,
                                                               sums, cnt, vlist, WB);
        full_kernel<false><<<Bn*BPB, 256, 0, stream>>>(x, mask, Wi1, bi1, Wi2, bi2, We,
                                                       Wo1, bo1, Wo2, bo2, sums, WB, out);
    }
}